// Round 13
// baseline (237.311 us; speedup 1.0000x reference)
//
#include <hip/hip_runtime.h>
#include <hip/hip_bf16.h>
#include <math.h>

// Problem constants (fixed by reference setup)
#define S_LEN   1024
#define BATCH   2
#define DMODEL  1024
#define NHEADS  16
#define HDIM    64
#define BHEADS  32          // BATCH*NHEADS
#define LP1     4           // 1 + L layers
#define ROWS_PL 2048        // S*B rows per layer

typedef __attribute__((ext_vector_type(8)))  short bf16x8;   // 8 bf16 = 4 VGPRs
typedef __attribute__((ext_vector_type(4)))  float f32x4;
typedef __attribute__((ext_vector_type(16))) float f32x16;

__device__ inline ushort bf16_rne(float a) {
    unsigned u = __float_as_uint(a);
    return (ushort)((u + 0x7FFFu + ((u >> 16) & 1u)) >> 16);
}
__device__ inline float bf16_up(ushort h) { return __uint_as_float(((unsigned)h) << 16); }
__device__ inline void split_bf16(float a, ushort &hi, ushort &lo) {
    hi = bf16_rne(a);
    lo = bf16_rne(a - bf16_up(hi));
}
// packed f32x2 -> bf16x2 (v_cvt_pk_bf16_f32)
__device__ inline uint pk_bf16(float a, float b) {
    float2 f; f.x = a; f.y = b;
    __hip_bfloat162 h = __float22bfloat162_rn(f);
    return *reinterpret_cast<uint*>(&h);
}
// raw v_exp_f32 (no denormal fixup path)
#if __has_builtin(__builtin_amdgcn_exp2f)
__device__ inline float fast_exp2(float x) { return __builtin_amdgcn_exp2f(x); }
#else
__device__ inline float fast_exp2(float x) { return exp2f(x); }
#endif

// v_permlane32_swap_b32 a, b:  a[32:63] <- b[0:31] ; b[0:31] <- a[32:63]
// (verified on HW in rounds 2-12: passed with identical absmax)
__device__ inline void permswap(uint &a, uint &b) {
    asm("v_permlane32_swap_b32 %0, %1" : "+v"(a), "+v"(b));
}

// Async global->LDS, 16 B per lane. HW places lane i at lds_base + i*16.
__device__ inline void glds16(const ushort* g, ushort* l) {
    __builtin_amdgcn_global_load_lds(
        (const __attribute__((address_space(1))) void*)g,
        (__attribute__((address_space(3))) void*)l, 16, 0, 0);
}

// hd^-0.5 * log2(e), folded into the Q projection epilogue
#define SCLF 0.18033688011112042f

// ---------------------------------------------------------------------------
// One-shot pre-split, flat exact grid (no idle blocks):
//   bid    0..1023  -> x        -> XsH
//   bid 1024..4095  -> lo       -> XsH+2M
//   bid 4096..6143  -> weights: z=(bid-4096)>>9 in {Wq,Wk,Wv,Wo}, hi plane;
//                      Wq/Wo also write the lo plane (WL).
// ---------------------------------------------------------------------------
__global__ __launch_bounds__(256)
void presplit(const float* __restrict__ x, const float* __restrict__ lo,
              const float* __restrict__ Wq, const float* __restrict__ Wk,
              const float* __restrict__ Wv, const float* __restrict__ Wo,
              ushort* __restrict__ XsH, ushort* __restrict__ WH,
              ushort* __restrict__ WL)
{
    const int bid = blockIdx.x;
    const float* src; ushort* dh; ushort* dl = nullptr; int local;
    if (bid < 1024)      { src = x;  dh = XsH;           local = bid; }
    else if (bid < 4096) { src = lo; dh = XsH + 2097152; local = bid - 1024; }
    else {
        const int z = (bid - 4096) >> 9;          // 0..3 -> Wq,Wk,Wv,Wo
        local = (bid - 4096) & 511;
        const float* wsrc[4] = { Wq, Wk, Wv, Wo };
        src = wsrc[z];
        dh = WH + (size_t)z * 1048576;
        if (z == 0 || z == 3) dl = WL + (size_t)z * 1048576;
    }
    const int i = (local * 256 + threadIdx.x) * 8;
    float v[8];
    *(float4*)&v[0] = *(const float4*)(src + i);
    *(float4*)&v[4] = *(const float4*)(src + i + 4);
    ushort h[8];
    #pragma unroll
    for (int j = 0; j < 8; ++j) h[j] = bf16_rne(v[j]);
    *(uint4*)(dh + i) = *(uint4*)h;
    if (dl) {
        ushort l[8];
        #pragma unroll
        for (int j = 0; j < 8; ++j) l[j] = bf16_rne(v[j] - bf16_up(h[j]));
        *(uint4*)(dl + i) = *(uint4*)l;
    }
}

// ---------------------------------------------------------------------------
// MERGED Q + KV projection, one dispatch. LPT ordering: KV blocks (4x work)
// at bid 0..511; Q blocks 512..1023 fill the tail.
// XCD-AWARE SWIZZLE (T1): bid&7 selects the XCD (HW round-robin), so each
// XCD owns a contiguous panel group whose working set fits its private L2:
//   KV: 8 m-panels (2 MB A) x all 8 n-tiles + 4 MB weights.
//   Q : 4 m-tiles x all 16 n-tiles.
// Round-12 counters showed 86 MB FETCH (vs 24 MB unique): the A panel was
// fetched ~8x because its 8 sharers landed on 8 different L2s.
// glds-staged, double-buffered, XOR chunk swizzle on frag reads.
// ---------------------------------------------------------------------------
__global__ __launch_bounds__(256, 2)
void proj_qkv(const ushort* __restrict__ XsH,
              const ushort* __restrict__ WH, const ushort* __restrict__ WL,
              const float* __restrict__ bq, const float* __restrict__ bk,
              const float* __restrict__ bv,
              ushort* __restrict__ qhb, ushort* __restrict__ qlb,
              ushort* __restrict__ kout, ushort* __restrict__ vout)
{
    __shared__ ushort smem[2][12288];    // 48 KB total; Q path uses 12 KB of it
    const int bid = blockIdx.x;
    const int t   = threadIdx.x;
    const int wv  = t >> 6, lane = t & 63;
    const int quad = lane >> 4, r = lane & 15;
    const int lrow = lane >> 2;
    const int lch  = ((lane & 3) ^ (lrow & 3) ^ ((lrow >> 2) & 3)) * 8;
    const int q0x  = ((quad ^ (r & 3) ^ ((r >> 2) & 3)) << 3);
    const int cn   = lane & 15;

    if (bid >= 512) {
        // =============== Q path (BM=BN=64, hi+lo weights) ===============
        // XCD-grouped: xcd = fid&7 owns m-tiles [xcd*4, xcd*4+4) x 16 n-tiles.
        const int fid = bid - 512;
        const int xcd = fid & 7, idx = fid >> 3;     // idx in [0,64)
        const int mt  = xcd * 4 + (idx >> 4);        // 0..31
        const int nt  = idx & 15;                    // 0..15
        const int m0 = mt * 64, n0 = nt * 64;

        const int wm = wv & 1, wn = wv >> 1;
        const int mBase = wm * 32, nBase = wn * 32;

        const ushort* Asrc  = XsH + (size_t)(m0 + wv * 16 + lrow) * DMODEL + lch;
        const ushort* Bhsrc = WH  + (size_t)(n0 + wv * 16 + lrow) * DMODEL + lch;
        const ushort* Blsrc = WL  + (size_t)(n0 + wv * 16 + lrow) * DMODEL + lch;

        f32x4 acc[2][2];
        #pragma unroll
        for (int i = 0; i < 2; ++i)
            #pragma unroll
            for (int j = 0; j < 2; ++j) acc[i][j] = (f32x4){0.f, 0.f, 0.f, 0.f};

        glds16(Asrc,  smem[0]        + wv * 512);
        glds16(Bhsrc, smem[0] + 2048 + wv * 512);
        glds16(Blsrc, smem[0] + 4096 + wv * 512);

        for (int k = 0; k < 32; ++k) {
            const int cur = k & 1;
            __syncthreads();
            if (k + 1 < 32) {
                const int off = (k + 1) * 32;
                glds16(Asrc  + off, smem[cur ^ 1]        + wv * 512);
                glds16(Bhsrc + off, smem[cur ^ 1] + 2048 + wv * 512);
                glds16(Blsrc + off, smem[cur ^ 1] + 4096 + wv * 512);
            }
            const ushort* Ah = smem[cur];
            const ushort* Bh = smem[cur] + 2048;
            const ushort* Bl = smem[cur] + 4096;
            bf16x8 fa[2], fbh[2], fbl[2];
            #pragma unroll
            for (int i = 0; i < 2; ++i)
                fa[i] = *(const bf16x8*)&Ah[(mBase + i * 16 + r) * 32 + q0x];
            #pragma unroll
            for (int j = 0; j < 2; ++j) {
                fbh[j] = *(const bf16x8*)&Bh[(nBase + j * 16 + r) * 32 + q0x];
                fbl[j] = *(const bf16x8*)&Bl[(nBase + j * 16 + r) * 32 + q0x];
            }
            #pragma unroll
            for (int i = 0; i < 2; ++i)
                #pragma unroll
                for (int j = 0; j < 2; ++j) {
                    acc[i][j] = __builtin_amdgcn_mfma_f32_16x16x32_bf16(fa[i], fbh[j], acc[i][j], 0, 0, 0);
                    acc[i][j] = __builtin_amdgcn_mfma_f32_16x16x32_bf16(fa[i], fbl[j], acc[i][j], 0, 0, 0);
                }
        }

        #pragma unroll
        for (int j = 0; j < 2; ++j) {
            const int n = n0 + nBase + j * 16 + cn;
            const float bvv = bq[n];
            #pragma unroll
            for (int i = 0; i < 2; ++i) {
                const int mrow = m0 + mBase + i * 16 + quad * 4;
                #pragma unroll
                for (int g = 0; g < 4; ++g) {
                    const int m = mrow + g;
                    const float val = (acc[i][j][g] + bvv) * SCLF;  // fold attn scale
                    const int s = m >> 1, b = m & 1;
                    const int bh = b * 16 + (n >> 6), e = n & 63;
                    const size_t idx2 = (((size_t)bh * S_LEN) + s) * HDIM + e;
                    ushort hi, lov; split_bf16(val, hi, lov);
                    qhb[idx2] = hi; qlb[idx2] = lov;
                }
            }
        }
    } else {
        // =============== KV path (BM=128, BN=128, hi-only) ===============
        // XCD-grouped: xcd = bid&7 owns m-panels [xcd*8, xcd*8+8) x 8 n-tiles.
        const int xcd = bid & 7, idx = bid >> 3;     // idx in [0,64)
        const int mt  = xcd * 8 + (idx >> 3);        // 0..63
        const int nt  = idx & 7;                     // 0..7
        const int m0 = mt * 128, n0 = nt * 128;
        const int lyr = m0 >> 11;

        const int wm = wv & 1, wn = wv >> 1;
        const int mBase = wm * 64, nBase = wn * 64;

        const ushort* KWh = WH + 1048576;
        const ushort* VWh = WH + 2097152;
        const ushort* Asrc0 = XsH + (size_t)(m0 + wv * 16 + lrow) * DMODEL + lch;
        const ushort* Asrc1 = Asrc0 + (size_t)64 * DMODEL;
        const ushort* Bw[2] = { KWh, VWh };
        const ushort* Bsrc[2][2];
        #pragma unroll
        for (int p = 0; p < 2; ++p)
            #pragma unroll
            for (int seg = 0; seg < 2; ++seg)
                Bsrc[p][seg] = Bw[p] + (size_t)(n0 + wv * 32 + seg * 16 + lrow) * DMODEL + lch;

        f32x4 aK[4][4], aV[4][4];
        #pragma unroll
        for (int i = 0; i < 4; ++i)
            #pragma unroll
            for (int j = 0; j < 4; ++j) {
                aK[i][j] = (f32x4){0.f, 0.f, 0.f, 0.f};
                aV[i][j] = (f32x4){0.f, 0.f, 0.f, 0.f};
            }

        // LDS per buffer: A[128][32] at 0, K-plane[128][32] at 4096, V at 8192
        glds16(Asrc0, smem[0]        + wv * 512);
        glds16(Asrc1, smem[0] + 2048 + wv * 512);
        #pragma unroll
        for (int p = 0; p < 2; ++p)
            #pragma unroll
            for (int seg = 0; seg < 2; ++seg)
                glds16(Bsrc[p][seg], smem[0] + 4096 + p * 4096 + (wv * 2 + seg) * 512);

        for (int k = 0; k < 32; ++k) {
            const int cur = k & 1;
            __syncthreads();
            if (k + 1 < 32) {
                const int off = (k + 1) * 32;
                glds16(Asrc0 + off, smem[cur ^ 1]        + wv * 512);
                glds16(Asrc1 + off, smem[cur ^ 1] + 2048 + wv * 512);
                #pragma unroll
                for (int p = 0; p < 2; ++p)
                    #pragma unroll
                    for (int seg = 0; seg < 2; ++seg)
                        glds16(Bsrc[p][seg] + off,
                               smem[cur ^ 1] + 4096 + p * 4096 + (wv * 2 + seg) * 512);
            }
            const ushort* Ah = smem[cur];
            const ushort* Bp = smem[cur] + 4096;

            bf16x8 fa[4];
            #pragma unroll
            for (int i = 0; i < 4; ++i)
                fa[i] = *(const bf16x8*)&Ah[(mBase + i * 16 + r) * 32 + q0x];
            #pragma unroll
            for (int j = 0; j < 4; ++j) {
                const int off2 = (nBase + j * 16 + r) * 32 + q0x;
                const bf16x8 fkh = *(const bf16x8*)&Bp[off2];
                const bf16x8 fvh = *(const bf16x8*)&Bp[4096 + off2];
                #pragma unroll
                for (int i = 0; i < 4; ++i) {
                    aK[i][j] = __builtin_amdgcn_mfma_f32_16x16x32_bf16(fa[i], fkh, aK[i][j], 0, 0, 0);
                    aV[i][j] = __builtin_amdgcn_mfma_f32_16x16x32_bf16(fa[i], fvh, aV[i][j], 0, 0, 0);
                }
            }
        }

        // ---- K epilogue: fragment-linear [bhI][kt][es][lane][8] ----
        #pragma unroll
        for (int j = 0; j < 4; ++j) {
            const int n = n0 + nBase + j * 16 + cn;
            const float bb = bk[n];
            const int e    = n & 63;
            const int es_k = e >> 4, half_k = (e >> 3) & 1, j_k = e & 7;
            const int h    = n >> 6;
            #pragma unroll
            for (int i = 0; i < 4; ++i) {
                #pragma unroll
                for (int g = 0; g < 4; ++g) {
                    const int m = m0 + mBase + i * 16 + quad * 4 + g;
                    const int rem = m & 2047, s = rem >> 1, b = rem & 1;
                    const int bhI = lyr * 32 + b * 16 + h;
                    const int kt  = s >> 5;
                    const int lnk = half_k * 32 + (s & 31);
                    kout[(size_t)bhI * 65536 + (size_t)(kt * 4 + es_k) * 512 + lnk * 8 + j_k]
                        = bf16_rne(aK[i][j][g] + bb);
                }
            }
        }

        // ---- V epilogue: transpose via LDS [128][130], fragment-linear ----
        ushort* T = &smem[0][0];   // 128*130 = 16,640 ushorts <= 24,576 total
        __syncthreads();
        #pragma unroll
        for (int j = 0; j < 4; ++j) {
            const int nloc = nBase + j * 16 + cn;
            const float bb = bv[n0 + nloc];
            #pragma unroll
            for (int i = 0; i < 4; ++i) {
                #pragma unroll
                for (int g = 0; g < 4; ++g) {
                    const int mloc = mBase + i * 16 + quad * 4 + g;
                    T[nloc * 130 + mloc] = bf16_rne(aV[i][j][g] + bb);
                }
            }
        }
        __syncthreads();
        {
            const int nloc = t >> 1, bsel = t & 1;
            const int n = n0 + nloc, h = n >> 6;
            const int e = n & 63;
            const int dg = e >> 5, lid_v = e & 31;
            const int s0g = (m0 & 2047) >> 1;      // multiple of 64
            const int kt0 = s0g >> 5;
            const int bhI = lyr * 32 + bsel * 16 + h;
            #pragma unroll
            for (int c = 0; c < 8; ++c) {
                ushort tmp[8];
                #pragma unroll
                for (int j = 0; j < 8; ++j)
                    tmp[j] = T[nloc * 130 + 2 * (c * 8 + j) + bsel];
                const int kt = kt0 + (c >> 2);
                const int c2 = c & 3;
                const int ks = c2 >> 1, hv = c2 & 1;
                ushort* dstb = vout + (size_t)bhI * 65536 + (size_t)kt * 2048;
                *(uint4*)(dstb + (ks * 2 + dg) * 512 + (hv * 32 + lid_v) * 8) = *(uint4*)tmp;
            }
        }
    }
}

// ---------------------------------------------------------------------------
// O projection, glds staging, double-buffered, XOR swizzle.
// BM=BN=64, BK=32, 256 thr. fp32 row-major out[m][n].
// ---------------------------------------------------------------------------
__global__ __launch_bounds__(256)
void proj_o(const ushort* __restrict__ Abf,
            const ushort* __restrict__ Bhg, const ushort* __restrict__ Blg,
            const float* __restrict__ bias, float* __restrict__ outf)
{
    __shared__ ushort smem[2][3 * 2048];   // dbuf x {Ah, Bh, Bl}: 24 KB

    const int fid = blockIdx.x;
    const int nt = (fid & 7) * 2 + ((fid >> 3) & 1);
    const int mt = fid >> 4;
    const int m0 = mt * 64, n0 = nt * 64;

    const int t  = threadIdx.x;
    const int wv = t >> 6, lane = t & 63;
    const int quad = lane >> 4, r = lane & 15;
    const int wm = wv & 1, wn = wv >> 1;
    const int mBase = wm * 32, nBase = wn * 32;

    const int lrow = lane >> 2;
    const int lch  = ((lane & 3) ^ (lrow & 3) ^ ((lrow >> 2) & 3)) * 8;
    const ushort* Asrc  = Abf + (size_t)(m0 + wv * 16 + lrow) * DMODEL + lch;
    const ushort* Bhsrc = Bhg + (size_t)(n0 + wv * 16 + lrow) * DMODEL + lch;
    const ushort* Blsrc = Blg + (size_t)(n0 + wv * 16 + lrow) * DMODEL + lch;

    const int q0x = ((quad ^ (r & 3) ^ ((r >> 2) & 3)) << 3);
    f32x4 acc[2][2];
    #pragma unroll
    for (int i = 0; i < 2; ++i)
        #pragma unroll
        for (int j = 0; j < 2; ++j) acc[i][j] = (f32x4){0.f, 0.f, 0.f, 0.f};

    glds16(Asrc,  smem[0]        + wv * 512);
    glds16(Bhsrc, smem[0] + 2048 + wv * 512);
    glds16(Blsrc, smem[0] + 4096 + wv * 512);

    for (int k = 0; k < 32; ++k) {
        const int cur = k & 1;
        __syncthreads();
        if (k + 1 < 32) {
            const int off = (k + 1) * 32;
            glds16(Asrc  + off, smem[cur ^ 1]        + wv * 512);
            glds16(Bhsrc + off, smem[cur ^ 1] + 2048 + wv * 512);
            glds16(Blsrc + off, smem[cur ^ 1] + 4096 + wv * 512);
        }
        const ushort* Ah = smem[cur];
        const ushort* Bh = smem[cur] + 2048;
        const ushort* Bl = smem[cur] + 4096;
        bf16x8 fa[2], fbh[2], fbl[2];
        #pragma unroll
        for (int i = 0; i < 2; ++i)
            fa[i] = *(const bf16x8*)&Ah[(mBase + i * 16 + r) * 32 + q0x];
        #pragma unroll
        for (int j = 0; j < 2; ++j) {
            fbh[j] = *(const bf16x8*)&Bh[(nBase + j * 16 + r) * 32 + q0x];
            fbl[j] = *(const bf16x8*)&Bl[(nBase + j * 16 + r) * 32 + q0x];
        }
        #pragma unroll
        for (int i = 0; i < 2; ++i)
            #pragma unroll
            for (int j = 0; j < 2; ++j) {
                acc[i][j] = __builtin_amdgcn_mfma_f32_16x16x32_bf16(fa[i], fbh[j], acc[i][j], 0, 0, 0);
                acc[i][j] = __builtin_amdgcn_mfma_f32_16x16x32_bf16(fa[i], fbl[j], acc[i][j], 0, 0, 0);
            }
    }

    const int cn = lane & 15;
    #pragma unroll
    for (int j = 0; j < 2; ++j) {
        const int n = n0 + nBase + j * 16 + cn;
        const float bvv = bias[n];
        #pragma unroll
        for (int i = 0; i < 2; ++i) {
            const int mrow = m0 + mBase + i * 16 + quad * 4;
            #pragma unroll
            for (int g = 0; g < 4; ++g)
                outf[(size_t)(mrow + g) * DMODEL + n] = acc[i][j][g] + bvv;
        }
    }
}

// ---------------------------------------------------------------------------
// MFMA flash attention, swapped-operand layout (zero LDS, zero barriers),
// u=2 query tiles per wave (64 q), software-pipelined, FRAGMENT-LINEAR K/V
// (coalesced base+lane*16B loads). QK chains seeded with a persistent zero
// C-vector. Grid 512, XCD-swizzled. 2 waves/SIMD is the register-imposed
// occupancy ceiling (unified VGPR+AGPR footprint ~250/wave; round-11's
// (256,4) cap spilled to scratch: 2 GB traffic, 7x slower).
// ---------------------------------------------------------------------------
__global__ __launch_bounds__(256, 2)
void attn_mfma(const ushort* __restrict__ qhg, const ushort* __restrict__ qlg,
               const ushort* __restrict__ kh, const ushort* __restrict__ vth,
               const float* __restrict__ lwraw, float* __restrict__ part)
{
    const int t    = threadIdx.x;
    const int wv   = t >> 6, lane = t & 63;
    const int half = lane >> 5, lid = lane & 31;

    const int fid  = blockIdx.x;                 // 512 blocks
    const int xcd  = fid & 7, slot = fid >> 3;   // slot in [0,64)
    const int pair = xcd * 16 + (slot >> 2);     // 16 (bh,l) pairs per XCD
    const int qt   = slot & 3;                   // 4 q-tiles of 256 per pair
    const int bh   = pair & 31, l = pair >> 5;
    const int qbase = qt * 256 + wv * 64;        // wave owns 64 queries

    float wl;
    {
        float v[LP1], wm = -3.0e38f;
        #pragma unroll
        for (int i = 0; i < LP1; ++i) { v[i] = lwraw[i]; wm = fmaxf(wm, v[i]); }
        float ws = 0.f;
        #pragma unroll
        for (int i = 0; i < LP1; ++i) { v[i] = __expf(v[i] - wm); ws += v[i]; }
        wl = v[l] / ws;
    }

    // Q fragments (B-frag: lane owns query row qbase+u*32+lid, 8 dims/frag)
    bf16x8 qh[2][4], ql[2][4];
    #pragma unroll
    for (int u = 0; u < 2; ++u) {
        const size_t qoff = ((size_t)bh * S_LEN + qbase + u * 32 + lid) * HDIM + half * 8;
        #pragma unroll
        for (int es = 0; es < 4; ++es) {
            qh[u][es] = *(const bf16x8*)(qhg + qoff + es * 16);
            ql[u][es] = *(const bf16x8*)(qlg + qoff + es * 16);
        }
    }

    f32x16 o[2][2];
    #pragma unroll
    for (int u = 0; u < 2; ++u)
        #pragma unroll
        for (int dg = 0; dg < 2; ++dg)
            #pragma unroll
            for (int i = 0; i < 16; ++i) o[u][dg][i] = 0.f;
    float ls[2] = {0.f, 0.f};

    // persistent zero C-operand: seeds each QK chain, never re-written
    f32x16 zf;
    #pragma unroll
    for (int i = 0; i < 16; ++i) zf[i] = 0.f;

    // fragment-linear bases: every load below is base + lane*16B (coalesced)
    const size_t kvo = (size_t)(l * BHEADS + bh) * S_LEN * HDIM;
    const ushort* kfb = kh  + kvo + (size_t)lane * 8;
    const ushort* vfb = vth + kvo + (size_t)lane * 8;

    // ---- prologue: K(0) -> kb; sa = QK(K(0)); K(1) -> kn ----
    bf16x8 kb[4], kn[4];
    #pragma unroll
    for (int es = 0; es < 4; ++es)
        kb[es] = *(const bf16x8*)(kfb + es * 512);
    #pragma unroll
    for (int es = 0; es < 4; ++es)
        kn[es] = *(const bf16x8*)(kfb + 2048 + es * 512);

    f32x16 sa[2];
    #pragma unroll
    for (int es = 0; es < 4; ++es)
        #pragma unroll
        for (int u = 0; u < 2; ++u) {
            sa[u] = __builtin_amdgcn_mfma_f32_32x32x16_bf16(kb[es], qh[u][es],
                                                            es == 0 ? zf : sa[u], 0, 0, 0);
            sa[u] = __builtin_amdgcn_mfma_f32_32x32x16_bf16(kb[es], ql[u][es], sa[u], 0, 0, 0);
        }

    for (int kt = 0; kt < 32; ++kt) {
        // ---- V(kt) loads: coalesced, issued early, consumed by PV ----
        bf16x8 vb[2][2];
        {
            const ushort* vp = vfb + (size_t)kt * 2048;
            #pragma unroll
            for (int ks = 0; ks < 2; ++ks)
                #pragma unroll
                for (int dg = 0; dg < 2; ++dg)
                    vb[ks][dg] = *(const bf16x8*)(vp + (ks * 2 + dg) * 512);
        }

        // ---- softmax(sa of kt) -> pf[2][2], ls; sa dead afterwards ----
        // sa[u] = S^T[k][q]: lane owns col q, reg r -> k=(r&3)+8*(r>>2)+4*half
        bf16x8 pf[2][2];
        #pragma unroll
        for (int ks = 0; ks < 2; ++ks) {
            #pragma unroll
            for (int u = 0; u < 2; ++u) {
                const float p0 = fast_exp2(sa[u][8 * ks + 0]);
                const float p1 = fast_exp2(sa[u][8 * ks + 1]);
                const float p2 = fast_exp2(sa[u][8 * ks + 2]);
                const float p3 = fast_exp2(sa[u][8 * ks + 3]);
                const float p4 = fast_exp2(sa[u][8 * ks + 4]);
                const float p5 = fast_exp2(sa[u][8 * ks + 5]);
                const float p6 = fast_exp2(sa[u][8 * ks + 6]);
                const float p7 = fast_exp2(sa[u][8 * ks + 7]);
                ls[u] += ((p0 + p1) + (p2 + p3)) + ((p4 + p5) + (p6 + p7));

                // Own regs (local k within the 16-key group):
                //   half=0: a0={0,1} a1={2,3} b0={8,9}  b1={10,11}
                //   half=1: a0={4,5} a1={6,7} b0={12,13} b1={14,15}
                // Lane needs k = half*8 + 0..7 of column q=lid.
                uint a0 = pk_bf16(p0, p1);
                uint a1 = pk_bf16(p2, p3);
                uint b0 = pk_bf16(p4, p5);
                uint b1 = pk_bf16(p6, p7);
                // a[32:63] <- b[0:31]; b[0:31] <- a[32:63]:
                //   a0 -> half0:{0,1}  half1:{8,9}   = W0
                //   b0 -> half0:{4,5}  half1:{12,13} = W2
                permswap(a0, b0);
                permswap(a1, b1);            // a1 = W1, b1 = W3
                union { uint w[4]; bf16x8 v; } pu;
                pu.w[0] = a0; pu.w[1] = a1; pu.w[2] = b0; pu.w[3] = b1;
                pf[ks][u] = pu.v;
            }
        }

        // ---- advance K: kb <- kn, prefetch K(kt+2), coalesced ----
        #pragma unroll
        for (int es = 0; es < 4; ++es) kb[es] = kn[es];
        {
            const ushort* kp = kfb + (size_t)((kt + 2) & 31) * 2048;
            #pragma unroll
            for (int es = 0; es < 4; ++es) kn[es] = *(const bf16x8*)(kp + es * 512);
        }

        // ---- QK(kt+1) -> sa (zf-seeded; kt=31 computes an unused tile) ----
        __builtin_amdgcn_s_setprio(1);
        #pragma unroll
        for (int es = 0; es < 4; ++es)
            #pragma unroll
            for (int u = 0; u < 2; ++u) {
                sa[u] = __builtin_amdgcn_mfma_f32_32x32x16_bf16(kb[es], qh[u][es],
                                                                es == 0 ? zf : sa[u], 0, 0, 0);
                sa[u] = __builtin_amdgcn_mfma_f32_32x32x16_bf16(kb[es], ql[u][es], sa[u], 0, 0, 0);
            }
        __builtin_amdgcn_s_setprio(0);

        // ---- PV(kt): o += V^T(kt) x P^T(kt) ----
        __builtin_amdgcn_s_setprio(1);
        #pragma unroll
        for (int ks = 0; ks < 2; ++ks)
            #pragma unroll
            for (int dg = 0; dg < 2; ++dg)
                #pragma unroll
                for (int u = 0; u < 2; ++u)
                    o[u][dg] = __builtin_amdgcn_mfma_f32_32x32x16_bf16(vb[ks][dg], pf[ks][u], o[u][dg], 0, 0, 0);
        __builtin_amdgcn_s_setprio(0);
    }

    // ---- epilogue: combine half-lane partial sums, scale, store O^T ----
    const int b = bh >> 4, hh = bh & 15;
    #pragma unroll
    for (int u = 0; u < 2; ++u) {
        float lsv = ls[u];
        lsv += __shfl_xor(lsv, 32);
        const float sc = wl / lsv;
        const int q = qbase + u * 32 + lid;
        float* pb = part + (size_t)l * (ROWS_PL * DMODEL)
                  + ((size_t)q * BATCH + b) * DMODEL + hh * HDIM;
        #pragma unroll
        for (int dg = 0; dg < 2; ++dg)
            #pragma unroll
            for (int rq = 0; rq < 4; ++rq) {
                float4 vv;
                vv.x = o[u][dg][rq * 4 + 0] * sc;
                vv.y = o[u][dg][rq * 4 + 1] * sc;
                vv.z = o[u][dg][rq * 4 + 2] * sc;
                vv.w = o[u][dg][rq * 4 + 3] * sc;
                *(float4*)(pb + dg * 32 + rq * 8 + half * 4) = vv;
            }
    }
}

// ---------------------------------------------------------------------------
// Sum the 4 layer partials -> bf16 hi plane for the O projection.
// ---------------------------------------------------------------------------
__global__ __launch_bounds__(256)
void sum_y(const float* __restrict__ part, ushort* __restrict__ YH)
{
    const int i = (blockIdx.x * 256 + threadIdx.x) * 8;
    float acc[8];
    #pragma unroll
    for (int c = 0; c < 2; ++c) {
        float4 s = *(const float4*)(part + i + c * 4);
        #pragma unroll
        for (int l = 1; l < LP1; ++l) {
            const float4 p = *(const float4*)(part + (size_t)l * 2097152 + i + c * 4);
            s.x += p.x; s.y += p.y; s.z += p.z; s.w += p.w;
        }
        acc[c * 4 + 0] = s.x; acc[c * 4 + 1] = s.y;
        acc[c * 4 + 2] = s.z; acc[c * 4 + 3] = s.w;
    }
    uint out[4];
    #pragma unroll
    for (int c = 0; c < 4; ++c) out[c] = pk_bf16(acc[c * 2], acc[c * 2 + 1]);
    *(uint4*)(YH + i) = *(uint4*)out;
}

// ---------------------------------------------------------------------------
extern "C" void kernel_launch(void* const* d_in, const int* in_sizes, int n_in,
                              void* d_out, int out_size, void* d_ws, size_t ws_size,
                              hipStream_t stream) {
    const float* x  = (const float*)d_in[0];
    const float* lo = (const float*)d_in[1];
    const float* Wq = (const float*)d_in[2];
    const float* bq = (const float*)d_in[3];
    const float* Wk = (const float*)d_in[4];
    const float* bk = (const float*)d_in[5];
    const float* Wv = (const float*)d_in[6];
    const float* bv = (const float*)d_in[7];
    const float* Wo = (const float*)d_in[8];
    const float* bo = (const float*)d_in[9];
    const float* lw = (const float*)d_in[10];
    float* out = (float*)d_out;

    char* ws = (char*)d_ws;
    ushort* XsH  = (ushort*)(ws);                          // 16,777,216 B
    ushort* WH   = (ushort*)(ws + 16777216);               //  8,388,608 B
    ushort* WL   = (ushort*)(ws + 25165824);               //  8,388,608 B (Wq/Wo only)
    ushort* qhb  = (ushort*)(ws + 33554432);               //  4,194,304 B
    ushort* qlb  = (ushort*)(ws + 37748736);               //  4,194,304 B
    ushort* khb  = (ushort*)(ws + 41943040);               // 16,777,216 B
    ushort* vthb = (ushort*)(ws + 58720256);               // 16,777,216 B
    float*  part = (float*)(ws + 75497472);                // 33,554,432 B
    ushort* YH   = (ushort*)(ws + 109051904);              //  4,194,304 B
    // total 113,246,208 B

    dim3 blk(256);
    // Xs -> hi plane; Wq/Wo -> hi+lo; Wk/Wv -> hi only (flat exact grid)
    presplit<<<dim3(6144), blk, 0, stream>>>(x, lo, Wq, Wk, Wv, Wo, XsH, WH, WL);
    // merged Q + KV projections (LPT + XCD-aware panel grouping)
    proj_qkv<<<dim3(1024), blk, 0, stream>>>(XsH, WH, WL, bq, bk, bv,
                                             qhb, qlb, khb, vthb);
    // attention: 512 XCD-swizzled blocks -> per-layer fp32 partials
    attn_mfma<<<dim3(512), blk, 0, stream>>>(qhb, qlb, khb, vthb, lw, part);
    // reduce 4 partials -> bf16 hi plane
    sum_y<<<dim3(1024), blk, 0, stream>>>(part, YH);
    // output projection (glds dbuf)
    proj_o<<<dim3(512), blk, 0, stream>>>(YH, WH + 3145728, WL + 3145728, bo, out);
}

// Round 14
// 236.153 us; speedup vs baseline: 1.0049x; 1.0049x over previous
//
#include <hip/hip_runtime.h>
#include <hip/hip_bf16.h>
#include <math.h>

// Problem constants (fixed by reference setup)
#define S_LEN   1024
#define BATCH   2
#define DMODEL  1024
#define NHEADS  16
#define HDIM    64
#define BHEADS  32          // BATCH*NHEADS
#define LP1     4           // 1 + L layers
#define ROWS_PL 2048        // S*B rows per layer

typedef __attribute__((ext_vector_type(8)))  short bf16x8;   // 8 bf16 = 4 VGPRs
typedef __attribute__((ext_vector_type(4)))  float f32x4;
typedef __attribute__((ext_vector_type(16))) float f32x16;

__device__ inline ushort bf16_rne(float a) {
    unsigned u = __float_as_uint(a);
    return (ushort)((u + 0x7FFFu + ((u >> 16) & 1u)) >> 16);
}
__device__ inline float bf16_up(ushort h) { return __uint_as_float(((unsigned)h) << 16); }
__device__ inline void split_bf16(float a, ushort &hi, ushort &lo) {
    hi = bf16_rne(a);
    lo = bf16_rne(a - bf16_up(hi));
}
// packed f32x2 -> bf16x2 (v_cvt_pk_bf16_f32)
__device__ inline uint pk_bf16(float a, float b) {
    float2 f; f.x = a; f.y = b;
    __hip_bfloat162 h = __float22bfloat162_rn(f);
    return *reinterpret_cast<uint*>(&h);
}
// raw v_exp_f32 (no denormal fixup path)
#if __has_builtin(__builtin_amdgcn_exp2f)
__device__ inline float fast_exp2(float x) { return __builtin_amdgcn_exp2f(x); }
#else
__device__ inline float fast_exp2(float x) { return exp2f(x); }
#endif

// v_permlane32_swap_b32 a, b:  a[32:63] <- b[0:31] ; b[0:31] <- a[32:63]
// (verified on HW in rounds 2-13: passed with identical absmax)
__device__ inline void permswap(uint &a, uint &b) {
    asm("v_permlane32_swap_b32 %0, %1" : "+v"(a), "+v"(b));
}

// Async global->LDS, 16 B per lane. HW places lane i at lds_base + i*16.
__device__ inline void glds16(const ushort* g, ushort* l) {
    __builtin_amdgcn_global_load_lds(
        (const __attribute__((address_space(1))) void*)g,
        (__attribute__((address_space(3))) void*)l, 16, 0, 0);
}

// hd^-0.5 * log2(e), folded into the Q projection epilogue
#define SCLF 0.18033688011112042f

// ---------------------------------------------------------------------------
// One-shot pre-split, flat exact grid (no idle blocks):
//   bid    0..1023  -> x        -> XsH
//   bid 1024..4095  -> lo       -> XsH+2M
//   bid 4096..6143  -> weights: z=(bid-4096)>>9 in {Wq,Wk,Wv,Wo}, hi plane;
//                      Wq/Wo also write the lo plane (WL).
// ---------------------------------------------------------------------------
__global__ __launch_bounds__(256)
void presplit(const float* __restrict__ x, const float* __restrict__ lo,
              const float* __restrict__ Wq, const float* __restrict__ Wk,
              const float* __restrict__ Wv, const float* __restrict__ Wo,
              ushort* __restrict__ XsH, ushort* __restrict__ WH,
              ushort* __restrict__ WL)
{
    const int bid = blockIdx.x;
    const float* src; ushort* dh; ushort* dl = nullptr; int local;
    if (bid < 1024)      { src = x;  dh = XsH;           local = bid; }
    else if (bid < 4096) { src = lo; dh = XsH + 2097152; local = bid - 1024; }
    else {
        const int z = (bid - 4096) >> 9;          // 0..3 -> Wq,Wk,Wv,Wo
        local = (bid - 4096) & 511;
        const float* wsrc[4] = { Wq, Wk, Wv, Wo };
        src = wsrc[z];
        dh = WH + (size_t)z * 1048576;
        if (z == 0 || z == 3) dl = WL + (size_t)z * 1048576;
    }
    const int i = (local * 256 + threadIdx.x) * 8;
    float v[8];
    *(float4*)&v[0] = *(const float4*)(src + i);
    *(float4*)&v[4] = *(const float4*)(src + i + 4);
    ushort h[8];
    #pragma unroll
    for (int j = 0; j < 8; ++j) h[j] = bf16_rne(v[j]);
    *(uint4*)(dh + i) = *(uint4*)h;
    if (dl) {
        ushort l[8];
        #pragma unroll
        for (int j = 0; j < 8; ++j) l[j] = bf16_rne(v[j] - bf16_up(h[j]));
        *(uint4*)(dl + i) = *(uint4*)l;
    }
}

// ---------------------------------------------------------------------------
// MERGED Q + KV projection, one dispatch, grid 768. LPT: KV blocks (bid
// 0..511) first, Q blocks (512..767) fill the tail. Both paths BM=128
// (16+ MFMA per wave per K-step: attacks the measured 25%-MfmaUtil
// latency-bound regime with more math per barrier+stage cycle).
// XCD-aware grouping (bid&7 = HW XCD) keeps each A-panel resident in one
// L2 (round 13: FETCH 86 -> 43 MB). glds-staged, double-buffered.
//
// bid <  512 -> KV path: BM=128, BN=128, hi-only weights, K and V fused.
//   K out: fragment-linear khb[bhI][kt][es][lane][8],  lane=half*32+(s&31)
//   V out: LDS transpose -> vthb[bhI][kt][ks*2+dg][lane][8], lane=half*32+(e&31)
// bid >= 512 -> Q path: BM=128, BN=64, hi+lo weights, scaled, split into
//   hi/lo planes at [b*16+h][s][e]   (256 blocks)
// ---------------------------------------------------------------------------
__global__ __launch_bounds__(256, 2)
void proj_qkv(const ushort* __restrict__ XsH,
              const ushort* __restrict__ WH, const ushort* __restrict__ WL,
              const float* __restrict__ bq, const float* __restrict__ bk,
              const float* __restrict__ bv,
              ushort* __restrict__ qhb, ushort* __restrict__ qlb,
              ushort* __restrict__ kout, ushort* __restrict__ vout)
{
    __shared__ ushort smem[2][12288];    // 48 KB total; Q path uses 32 KB of it
    const int bid = blockIdx.x;
    const int t   = threadIdx.x;
    const int wv  = t >> 6, lane = t & 63;
    const int quad = lane >> 4, r = lane & 15;
    const int lrow = lane >> 2;
    const int lch  = ((lane & 3) ^ (lrow & 3) ^ ((lrow >> 2) & 3)) * 8;
    const int q0x  = ((quad ^ (r & 3) ^ ((r >> 2) & 3)) << 3);
    const int cn   = lane & 15;

    if (bid >= 512) {
        // ========== Q path (BM=128, BN=64, hi+lo weights) ==========
        // XCD-grouped: xcd owns m-panels [xcd*2, xcd*2+2) x 16 n-tiles.
        const int fid = bid - 512;                   // 0..255; bid%8 == fid%8
        const int xcd = fid & 7, idx = fid >> 3;     // idx in [0,32)
        const int mt  = xcd * 2 + (idx >> 4);        // 0..15
        const int nt  = idx & 15;                    // 0..15
        const int m0 = mt * 128, n0 = nt * 64;

        const int wm = wv & 1, wn = wv >> 1;
        const int mBase = wm * 64, nBase = wn * 32;

        const ushort* Asrc0 = XsH + (size_t)(m0 + wv * 16 + lrow) * DMODEL + lch;
        const ushort* Asrc1 = Asrc0 + (size_t)64 * DMODEL;
        const ushort* Bhsrc = WH  + (size_t)(n0 + wv * 16 + lrow) * DMODEL + lch;
        const ushort* Blsrc = WL  + (size_t)(n0 + wv * 16 + lrow) * DMODEL + lch;

        f32x4 acc[4][2];
        #pragma unroll
        for (int i = 0; i < 4; ++i)
            #pragma unroll
            for (int j = 0; j < 2; ++j) acc[i][j] = (f32x4){0.f, 0.f, 0.f, 0.f};

        // LDS per buffer: A[128][32] at 0, Bh[64][32] at 4096, Bl at 6144
        glds16(Asrc0, smem[0]        + wv * 512);
        glds16(Asrc1, smem[0] + 2048 + wv * 512);
        glds16(Bhsrc, smem[0] + 4096 + wv * 512);
        glds16(Blsrc, smem[0] + 6144 + wv * 512);

        for (int k = 0; k < 32; ++k) {
            const int cur = k & 1;
            __syncthreads();
            if (k + 1 < 32) {
                const int off = (k + 1) * 32;
                glds16(Asrc0 + off, smem[cur ^ 1]        + wv * 512);
                glds16(Asrc1 + off, smem[cur ^ 1] + 2048 + wv * 512);
                glds16(Bhsrc + off, smem[cur ^ 1] + 4096 + wv * 512);
                glds16(Blsrc + off, smem[cur ^ 1] + 6144 + wv * 512);
            }
            const ushort* Ah = smem[cur];
            const ushort* Bh = smem[cur] + 4096;
            const ushort* Bl = smem[cur] + 6144;
            bf16x8 fa[4], fbh[2], fbl[2];
            #pragma unroll
            for (int i = 0; i < 4; ++i)
                fa[i] = *(const bf16x8*)&Ah[(mBase + i * 16 + r) * 32 + q0x];
            #pragma unroll
            for (int j = 0; j < 2; ++j) {
                fbh[j] = *(const bf16x8*)&Bh[(nBase + j * 16 + r) * 32 + q0x];
                fbl[j] = *(const bf16x8*)&Bl[(nBase + j * 16 + r) * 32 + q0x];
            }
            #pragma unroll
            for (int i = 0; i < 4; ++i)
                #pragma unroll
                for (int j = 0; j < 2; ++j) {
                    acc[i][j] = __builtin_amdgcn_mfma_f32_16x16x32_bf16(fa[i], fbh[j], acc[i][j], 0, 0, 0);
                    acc[i][j] = __builtin_amdgcn_mfma_f32_16x16x32_bf16(fa[i], fbl[j], acc[i][j], 0, 0, 0);
                }
        }

        #pragma unroll
        for (int j = 0; j < 2; ++j) {
            const int n = n0 + nBase + j * 16 + cn;
            const float bvv = bq[n];
            #pragma unroll
            for (int i = 0; i < 4; ++i) {
                const int mrow = m0 + mBase + i * 16 + quad * 4;
                #pragma unroll
                for (int g = 0; g < 4; ++g) {
                    const int m = mrow + g;
                    const float val = (acc[i][j][g] + bvv) * SCLF;  // fold attn scale
                    const int s = m >> 1, b = m & 1;
                    const int bh = b * 16 + (n >> 6), e = n & 63;
                    const size_t idx2 = (((size_t)bh * S_LEN) + s) * HDIM + e;
                    ushort hi, lov; split_bf16(val, hi, lov);
                    qhb[idx2] = hi; qlb[idx2] = lov;
                }
            }
        }
    } else {
        // =============== KV path (BM=128, BN=128, hi-only) ===============
        // XCD-grouped: xcd = bid&7 owns m-panels [xcd*8, xcd*8+8) x 8 n-tiles.
        const int xcd = bid & 7, idx = bid >> 3;     // idx in [0,64)
        const int mt  = xcd * 8 + (idx >> 3);        // 0..63
        const int nt  = idx & 7;                     // 0..7
        const int m0 = mt * 128, n0 = nt * 128;
        const int lyr = m0 >> 11;

        const int wm = wv & 1, wn = wv >> 1;
        const int mBase = wm * 64, nBase = wn * 64;

        const ushort* KWh = WH + 1048576;
        const ushort* VWh = WH + 2097152;
        const ushort* Asrc0 = XsH + (size_t)(m0 + wv * 16 + lrow) * DMODEL + lch;
        const ushort* Asrc1 = Asrc0 + (size_t)64 * DMODEL;
        const ushort* Bw[2] = { KWh, VWh };
        const ushort* Bsrc[2][2];
        #pragma unroll
        for (int p = 0; p < 2; ++p)
            #pragma unroll
            for (int seg = 0; seg < 2; ++seg)
                Bsrc[p][seg] = Bw[p] + (size_t)(n0 + wv * 32 + seg * 16 + lrow) * DMODEL + lch;

        f32x4 aK[4][4], aV[4][4];
        #pragma unroll
        for (int i = 0; i < 4; ++i)
            #pragma unroll
            for (int j = 0; j < 4; ++j) {
                aK[i][j] = (f32x4){0.f, 0.f, 0.f, 0.f};
                aV[i][j] = (f32x4){0.f, 0.f, 0.f, 0.f};
            }

        // LDS per buffer: A[128][32] at 0, K-plane[128][32] at 4096, V at 8192
        glds16(Asrc0, smem[0]        + wv * 512);
        glds16(Asrc1, smem[0] + 2048 + wv * 512);
        #pragma unroll
        for (int p = 0; p < 2; ++p)
            #pragma unroll
            for (int seg = 0; seg < 2; ++seg)
                glds16(Bsrc[p][seg], smem[0] + 4096 + p * 4096 + (wv * 2 + seg) * 512);

        for (int k = 0; k < 32; ++k) {
            const int cur = k & 1;
            __syncthreads();
            if (k + 1 < 32) {
                const int off = (k + 1) * 32;
                glds16(Asrc0 + off, smem[cur ^ 1]        + wv * 512);
                glds16(Asrc1 + off, smem[cur ^ 1] + 2048 + wv * 512);
                #pragma unroll
                for (int p = 0; p < 2; ++p)
                    #pragma unroll
                    for (int seg = 0; seg < 2; ++seg)
                        glds16(Bsrc[p][seg] + off,
                               smem[cur ^ 1] + 4096 + p * 4096 + (wv * 2 + seg) * 512);
            }
            const ushort* Ah = smem[cur];
            const ushort* Bp = smem[cur] + 4096;

            bf16x8 fa[4];
            #pragma unroll
            for (int i = 0; i < 4; ++i)
                fa[i] = *(const bf16x8*)&Ah[(mBase + i * 16 + r) * 32 + q0x];
            #pragma unroll
            for (int j = 0; j < 4; ++j) {
                const int off2 = (nBase + j * 16 + r) * 32 + q0x;
                const bf16x8 fkh = *(const bf16x8*)&Bp[off2];
                const bf16x8 fvh = *(const bf16x8*)&Bp[4096 + off2];
                #pragma unroll
                for (int i = 0; i < 4; ++i) {
                    aK[i][j] = __builtin_amdgcn_mfma_f32_16x16x32_bf16(fa[i], fkh, aK[i][j], 0, 0, 0);
                    aV[i][j] = __builtin_amdgcn_mfma_f32_16x16x32_bf16(fa[i], fvh, aV[i][j], 0, 0, 0);
                }
            }
        }

        // ---- K epilogue: fragment-linear [bhI][kt][es][lane][8] ----
        #pragma unroll
        for (int j = 0; j < 4; ++j) {
            const int n = n0 + nBase + j * 16 + cn;
            const float bb = bk[n];
            const int e    = n & 63;
            const int es_k = e >> 4, half_k = (e >> 3) & 1, j_k = e & 7;
            const int h    = n >> 6;
            #pragma unroll
            for (int i = 0; i < 4; ++i) {
                #pragma unroll
                for (int g = 0; g < 4; ++g) {
                    const int m = m0 + mBase + i * 16 + quad * 4 + g;
                    const int rem = m & 2047, s = rem >> 1, b = rem & 1;
                    const int bhI = lyr * 32 + b * 16 + h;
                    const int kt  = s >> 5;
                    const int lnk = half_k * 32 + (s & 31);
                    kout[(size_t)bhI * 65536 + (size_t)(kt * 4 + es_k) * 512 + lnk * 8 + j_k]
                        = bf16_rne(aK[i][j][g] + bb);
                }
            }
        }

        // ---- V epilogue: transpose via LDS [128][130], fragment-linear ----
        ushort* T = &smem[0][0];   // 128*130 = 16,640 ushorts <= 24,576 total
        __syncthreads();
        #pragma unroll
        for (int j = 0; j < 4; ++j) {
            const int nloc = nBase + j * 16 + cn;
            const float bb = bv[n0 + nloc];
            #pragma unroll
            for (int i = 0; i < 4; ++i) {
                #pragma unroll
                for (int g = 0; g < 4; ++g) {
                    const int mloc = mBase + i * 16 + quad * 4 + g;
                    T[nloc * 130 + mloc] = bf16_rne(aV[i][j][g] + bb);
                }
            }
        }
        __syncthreads();
        {
            const int nloc = t >> 1, bsel = t & 1;
            const int n = n0 + nloc, h = n >> 6;
            const int e = n & 63;
            const int dg = e >> 5, lid_v = e & 31;
            const int s0g = (m0 & 2047) >> 1;      // multiple of 64
            const int kt0 = s0g >> 5;
            const int bhI = lyr * 32 + bsel * 16 + h;
            #pragma unroll
            for (int c = 0; c < 8; ++c) {
                ushort tmp[8];
                #pragma unroll
                for (int j = 0; j < 8; ++j)
                    tmp[j] = T[nloc * 130 + 2 * (c * 8 + j) + bsel];
                const int kt = kt0 + (c >> 2);
                const int c2 = c & 3;
                const int ks = c2 >> 1, hv = c2 & 1;
                ushort* dstb = vout + (size_t)bhI * 65536 + (size_t)kt * 2048;
                *(uint4*)(dstb + (ks * 2 + dg) * 512 + (hv * 32 + lid_v) * 8) = *(uint4*)tmp;
            }
        }
    }
}

// ---------------------------------------------------------------------------
// O projection, BM=128, BN=64 (16 MFMA/wave/K-step), grid 256, XCD-grouped
// A-panels, glds-staged, double-buffered. fp32 row-major out[m][n].
// ---------------------------------------------------------------------------
__global__ __launch_bounds__(256)
void proj_o(const ushort* __restrict__ Abf,
            const ushort* __restrict__ Bhg, const ushort* __restrict__ Blg,
            const float* __restrict__ bias, float* __restrict__ outf)
{
    __shared__ ushort smem[2][8192];     // dbuf x {A 8K, Bh 4K, Bl 4K} = 32 KB

    const int fid = blockIdx.x;                  // 0..255
    const int xcd = fid & 7, idx = fid >> 3;     // idx in [0,32)
    const int mt  = xcd * 2 + (idx >> 4);        // 0..15
    const int nt  = idx & 15;                    // 0..15
    const int m0 = mt * 128, n0 = nt * 64;

    const int t  = threadIdx.x;
    const int wv = t >> 6, lane = t & 63;
    const int quad = lane >> 4, r = lane & 15;
    const int wm = wv & 1, wn = wv >> 1;
    const int mBase = wm * 64, nBase = wn * 32;

    const int lrow = lane >> 2;
    const int lch  = ((lane & 3) ^ (lrow & 3) ^ ((lrow >> 2) & 3)) * 8;
    const ushort* Asrc0 = Abf + (size_t)(m0 + wv * 16 + lrow) * DMODEL + lch;
    const ushort* Asrc1 = Asrc0 + (size_t)64 * DMODEL;
    const ushort* Bhsrc = Bhg + (size_t)(n0 + wv * 16 + lrow) * DMODEL + lch;
    const ushort* Blsrc = Blg + (size_t)(n0 + wv * 16 + lrow) * DMODEL + lch;

    const int q0x = ((quad ^ (r & 3) ^ ((r >> 2) & 3)) << 3);
    f32x4 acc[4][2];
    #pragma unroll
    for (int i = 0; i < 4; ++i)
        #pragma unroll
        for (int j = 0; j < 2; ++j) acc[i][j] = (f32x4){0.f, 0.f, 0.f, 0.f};

    glds16(Asrc0, smem[0]        + wv * 512);
    glds16(Asrc1, smem[0] + 2048 + wv * 512);
    glds16(Bhsrc, smem[0] + 4096 + wv * 512);
    glds16(Blsrc, smem[0] + 6144 + wv * 512);

    for (int k = 0; k < 32; ++k) {
        const int cur = k & 1;
        __syncthreads();
        if (k + 1 < 32) {
            const int off = (k + 1) * 32;
            glds16(Asrc0 + off, smem[cur ^ 1]        + wv * 512);
            glds16(Asrc1 + off, smem[cur ^ 1] + 2048 + wv * 512);
            glds16(Bhsrc + off, smem[cur ^ 1] + 4096 + wv * 512);
            glds16(Blsrc + off, smem[cur ^ 1] + 6144 + wv * 512);
        }
        const ushort* Ah = smem[cur];
        const ushort* Bh = smem[cur] + 4096;
        const ushort* Bl = smem[cur] + 6144;
        bf16x8 fa[4], fbh[2], fbl[2];
        #pragma unroll
        for (int i = 0; i < 4; ++i)
            fa[i] = *(const bf16x8*)&Ah[(mBase + i * 16 + r) * 32 + q0x];
        #pragma unroll
        for (int j = 0; j < 2; ++j) {
            fbh[j] = *(const bf16x8*)&Bh[(nBase + j * 16 + r) * 32 + q0x];
            fbl[j] = *(const bf16x8*)&Bl[(nBase + j * 16 + r) * 32 + q0x];
        }
        #pragma unroll
        for (int i = 0; i < 4; ++i)
            #pragma unroll
            for (int j = 0; j < 2; ++j) {
                acc[i][j] = __builtin_amdgcn_mfma_f32_16x16x32_bf16(fa[i], fbh[j], acc[i][j], 0, 0, 0);
                acc[i][j] = __builtin_amdgcn_mfma_f32_16x16x32_bf16(fa[i], fbl[j], acc[i][j], 0, 0, 0);
            }
    }

    const int cn = lane & 15;
    #pragma unroll
    for (int j = 0; j < 2; ++j) {
        const int n = n0 + nBase + j * 16 + cn;
        const float bvv = bias[n];
        #pragma unroll
        for (int i = 0; i < 4; ++i) {
            const int mrow = m0 + mBase + i * 16 + quad * 4;
            #pragma unroll
            for (int g = 0; g < 4; ++g)
                outf[(size_t)(mrow + g) * DMODEL + n] = acc[i][j][g] + bvv;
        }
    }
}

// ---------------------------------------------------------------------------
// MFMA flash attention, swapped-operand layout (zero LDS, zero barriers),
// u=2 query tiles per wave (64 q), software-pipelined, FRAGMENT-LINEAR K/V
// (coalesced base+lane*16B loads). QK chains seeded with a persistent zero
// C-vector. Grid 512, XCD-swizzled. 2 waves/SIMD is the register-imposed
// occupancy ceiling (unified VGPR+AGPR footprint ~250/wave; round-11's
// (256,4) cap spilled to scratch: 2 GB traffic, 7x slower).
// ---------------------------------------------------------------------------
__global__ __launch_bounds__(256, 2)
void attn_mfma(const ushort* __restrict__ qhg, const ushort* __restrict__ qlg,
               const ushort* __restrict__ kh, const ushort* __restrict__ vth,
               const float* __restrict__ lwraw, float* __restrict__ part)
{
    const int t    = threadIdx.x;
    const int wv   = t >> 6, lane = t & 63;
    const int half = lane >> 5, lid = lane & 31;

    const int fid  = blockIdx.x;                 // 512 blocks
    const int xcd  = fid & 7, slot = fid >> 3;   // slot in [0,64)
    const int pair = xcd * 16 + (slot >> 2);     // 16 (bh,l) pairs per XCD
    const int qt   = slot & 3;                   // 4 q-tiles of 256 per pair
    const int bh   = pair & 31, l = pair >> 5;
    const int qbase = qt * 256 + wv * 64;        // wave owns 64 queries

    float wl;
    {
        float v[LP1], wm = -3.0e38f;
        #pragma unroll
        for (int i = 0; i < LP1; ++i) { v[i] = lwraw[i]; wm = fmaxf(wm, v[i]); }
        float ws = 0.f;
        #pragma unroll
        for (int i = 0; i < LP1; ++i) { v[i] = __expf(v[i] - wm); ws += v[i]; }
        wl = v[l] / ws;
    }

    // Q fragments (B-frag: lane owns query row qbase+u*32+lid, 8 dims/frag)
    bf16x8 qh[2][4], ql[2][4];
    #pragma unroll
    for (int u = 0; u < 2; ++u) {
        const size_t qoff = ((size_t)bh * S_LEN + qbase + u * 32 + lid) * HDIM + half * 8;
        #pragma unroll
        for (int es = 0; es < 4; ++es) {
            qh[u][es] = *(const bf16x8*)(qhg + qoff + es * 16);
            ql[u][es] = *(const bf16x8*)(qlg + qoff + es * 16);
        }
    }

    f32x16 o[2][2];
    #pragma unroll
    for (int u = 0; u < 2; ++u)
        #pragma unroll
        for (int dg = 0; dg < 2; ++dg)
            #pragma unroll
            for (int i = 0; i < 16; ++i) o[u][dg][i] = 0.f;
    float ls[2] = {0.f, 0.f};

    // persistent zero C-operand: seeds each QK chain, never re-written
    f32x16 zf;
    #pragma unroll
    for (int i = 0; i < 16; ++i) zf[i] = 0.f;

    // fragment-linear bases: every load below is base + lane*16B (coalesced)
    const size_t kvo = (size_t)(l * BHEADS + bh) * S_LEN * HDIM;
    const ushort* kfb = kh  + kvo + (size_t)lane * 8;
    const ushort* vfb = vth + kvo + (size_t)lane * 8;

    // ---- prologue: K(0) -> kb; sa = QK(K(0)); K(1) -> kn ----
    bf16x8 kb[4], kn[4];
    #pragma unroll
    for (int es = 0; es < 4; ++es)
        kb[es] = *(const bf16x8*)(kfb + es * 512);
    #pragma unroll
    for (int es = 0; es < 4; ++es)
        kn[es] = *(const bf16x8*)(kfb + 2048 + es * 512);

    f32x16 sa[2];
    #pragma unroll
    for (int es = 0; es < 4; ++es)
        #pragma unroll
        for (int u = 0; u < 2; ++u) {
            sa[u] = __builtin_amdgcn_mfma_f32_32x32x16_bf16(kb[es], qh[u][es],
                                                            es == 0 ? zf : sa[u], 0, 0, 0);
            sa[u] = __builtin_amdgcn_mfma_f32_32x32x16_bf16(kb[es], ql[u][es], sa[u], 0, 0, 0);
        }

    for (int kt = 0; kt < 32; ++kt) {
        // ---- V(kt) loads: coalesced, issued early, consumed by PV ----
        bf16x8 vb[2][2];
        {
            const ushort* vp = vfb + (size_t)kt * 2048;
            #pragma unroll
            for (int ks = 0; ks < 2; ++ks)
                #pragma unroll
                for (int dg = 0; dg < 2; ++dg)
                    vb[ks][dg] = *(const bf16x8*)(vp + (ks * 2 + dg) * 512);
        }

        // ---- softmax(sa of kt) -> pf[2][2], ls; sa dead afterwards ----
        // sa[u] = S^T[k][q]: lane owns col q, reg r -> k=(r&3)+8*(r>>2)+4*half
        bf16x8 pf[2][2];
        #pragma unroll
        for (int ks = 0; ks < 2; ++ks) {
            #pragma unroll
            for (int u = 0; u < 2; ++u) {
                const float p0 = fast_exp2(sa[u][8 * ks + 0]);
                const float p1 = fast_exp2(sa[u][8 * ks + 1]);
                const float p2 = fast_exp2(sa[u][8 * ks + 2]);
                const float p3 = fast_exp2(sa[u][8 * ks + 3]);
                const float p4 = fast_exp2(sa[u][8 * ks + 4]);
                const float p5 = fast_exp2(sa[u][8 * ks + 5]);
                const float p6 = fast_exp2(sa[u][8 * ks + 6]);
                const float p7 = fast_exp2(sa[u][8 * ks + 7]);
                ls[u] += ((p0 + p1) + (p2 + p3)) + ((p4 + p5) + (p6 + p7));

                // Own regs (local k within the 16-key group):
                //   half=0: a0={0,1} a1={2,3} b0={8,9}  b1={10,11}
                //   half=1: a0={4,5} a1={6,7} b0={12,13} b1={14,15}
                // Lane needs k = half*8 + 0..7 of column q=lid.
                uint a0 = pk_bf16(p0, p1);
                uint a1 = pk_bf16(p2, p3);
                uint b0 = pk_bf16(p4, p5);
                uint b1 = pk_bf16(p6, p7);
                // a[32:63] <- b[0:31]; b[0:31] <- a[32:63]:
                //   a0 -> half0:{0,1}  half1:{8,9}   = W0
                //   b0 -> half0:{4,5}  half1:{12,13} = W2
                permswap(a0, b0);
                permswap(a1, b1);            // a1 = W1, b1 = W3
                union { uint w[4]; bf16x8 v; } pu;
                pu.w[0] = a0; pu.w[1] = a1; pu.w[2] = b0; pu.w[3] = b1;
                pf[ks][u] = pu.v;
            }
        }

        // ---- advance K: kb <- kn, prefetch K(kt+2), coalesced ----
        #pragma unroll
        for (int es = 0; es < 4; ++es) kb[es] = kn[es];
        {
            const ushort* kp = kfb + (size_t)((kt + 2) & 31) * 2048;
            #pragma unroll
            for (int es = 0; es < 4; ++es) kn[es] = *(const bf16x8*)(kp + es * 512);
        }

        // ---- QK(kt+1) -> sa (zf-seeded; kt=31 computes an unused tile) ----
        __builtin_amdgcn_s_setprio(1);
        #pragma unroll
        for (int es = 0; es < 4; ++es)
            #pragma unroll
            for (int u = 0; u < 2; ++u) {
                sa[u] = __builtin_amdgcn_mfma_f32_32x32x16_bf16(kb[es], qh[u][es],
                                                                es == 0 ? zf : sa[u], 0, 0, 0);
                sa[u] = __builtin_amdgcn_mfma_f32_32x32x16_bf16(kb[es], ql[u][es], sa[u], 0, 0, 0);
            }
        __builtin_amdgcn_s_setprio(0);

        // ---- PV(kt): o += V^T(kt) x P^T(kt) ----
        __builtin_amdgcn_s_setprio(1);
        #pragma unroll
        for (int ks = 0; ks < 2; ++ks)
            #pragma unroll
            for (int dg = 0; dg < 2; ++dg)
                #pragma unroll
                for (int u = 0; u < 2; ++u)
                    o[u][dg] = __builtin_amdgcn_mfma_f32_32x32x16_bf16(vb[ks][dg], pf[ks][u], o[u][dg], 0, 0, 0);
        __builtin_amdgcn_s_setprio(0);
    }

    // ---- epilogue: combine half-lane partial sums, scale, store O^T ----
    const int b = bh >> 4, hh = bh & 15;
    #pragma unroll
    for (int u = 0; u < 2; ++u) {
        float lsv = ls[u];
        lsv += __shfl_xor(lsv, 32);
        const float sc = wl / lsv;
        const int q = qbase + u * 32 + lid;
        float* pb = part + (size_t)l * (ROWS_PL * DMODEL)
                  + ((size_t)q * BATCH + b) * DMODEL + hh * HDIM;
        #pragma unroll
        for (int dg = 0; dg < 2; ++dg)
            #pragma unroll
            for (int rq = 0; rq < 4; ++rq) {
                float4 vv;
                vv.x = o[u][dg][rq * 4 + 0] * sc;
                vv.y = o[u][dg][rq * 4 + 1] * sc;
                vv.z = o[u][dg][rq * 4 + 2] * sc;
                vv.w = o[u][dg][rq * 4 + 3] * sc;
                *(float4*)(pb + dg * 32 + rq * 8 + half * 4) = vv;
            }
    }
}

// ---------------------------------------------------------------------------
// Sum the 4 layer partials -> bf16 hi plane for the O projection.
// ---------------------------------------------------------------------------
__global__ __launch_bounds__(256)
void sum_y(const float* __restrict__ part, ushort* __restrict__ YH)
{
    const int i = (blockIdx.x * 256 + threadIdx.x) * 8;
    float acc[8];
    #pragma unroll
    for (int c = 0; c < 2; ++c) {
        float4 s = *(const float4*)(part + i + c * 4);
        #pragma unroll
        for (int l = 1; l < LP1; ++l) {
            const float4 p = *(const float4*)(part + (size_t)l * 2097152 + i + c * 4);
            s.x += p.x; s.y += p.y; s.z += p.z; s.w += p.w;
        }
        acc[c * 4 + 0] = s.x; acc[c * 4 + 1] = s.y;
        acc[c * 4 + 2] = s.z; acc[c * 4 + 3] = s.w;
    }
    uint out[4];
    #pragma unroll
    for (int c = 0; c < 4; ++c) out[c] = pk_bf16(acc[c * 2], acc[c * 2 + 1]);
    *(uint4*)(YH + i) = *(uint4*)out;
}

// ---------------------------------------------------------------------------
extern "C" void kernel_launch(void* const* d_in, const int* in_sizes, int n_in,
                              void* d_out, int out_size, void* d_ws, size_t ws_size,
                              hipStream_t stream) {
    const float* x  = (const float*)d_in[0];
    const float* lo = (const float*)d_in[1];
    const float* Wq = (const float*)d_in[2];
    const float* bq = (const float*)d_in[3];
    const float* Wk = (const float*)d_in[4];
    const float* bk = (const float*)d_in[5];
    const float* Wv = (const float*)d_in[6];
    const float* bv = (const float*)d_in[7];
    const float* Wo = (const float*)d_in[8];
    const float* bo = (const float*)d_in[9];
    const float* lw = (const float*)d_in[10];
    float* out = (float*)d_out;

    char* ws = (char*)d_ws;
    ushort* XsH  = (ushort*)(ws);                          // 16,777,216 B
    ushort* WH   = (ushort*)(ws + 16777216);               //  8,388,608 B
    ushort* WL   = (ushort*)(ws + 25165824);               //  8,388,608 B (Wq/Wo only)
    ushort* qhb  = (ushort*)(ws + 33554432);               //  4,194,304 B
    ushort* qlb  = (ushort*)(ws + 37748736);               //  4,194,304 B
    ushort* khb  = (ushort*)(ws + 41943040);               // 16,777,216 B
    ushort* vthb = (ushort*)(ws + 58720256);               // 16,777,216 B
    float*  part = (float*)(ws + 75497472);                // 33,554,432 B
    ushort* YH   = (ushort*)(ws + 109051904);              //  4,194,304 B
    // total 113,246,208 B

    dim3 blk(256);
    // Xs -> hi plane; Wq/Wo -> hi+lo; Wk/Wv -> hi only (flat exact grid)
    presplit<<<dim3(6144), blk, 0, stream>>>(x, lo, Wq, Wk, Wv, Wo, XsH, WH, WL);
    // merged Q + KV projections (LPT + XCD grouping; Q path BM=128)
    proj_qkv<<<dim3(768), blk, 0, stream>>>(XsH, WH, WL, bq, bk, bv,
                                            qhb, qlb, khb, vthb);
    // attention: 512 XCD-swizzled blocks -> per-layer fp32 partials
    attn_mfma<<<dim3(512), blk, 0, stream>>>(qhb, qlb, khb, vthb, lw, part);
    // reduce 4 partials -> bf16 hi plane
    sum_y<<<dim3(1024), blk, 0, stream>>>(part, YH);
    // output projection (BM=128, XCD-grouped)
    proj_o<<<dim3(256), blk, 0, stream>>>(YH, WH + 3145728, WL + 3145728, bo, out);
}

// Round 15
// 231.849 us; speedup vs baseline: 1.0236x; 1.0186x over previous
//
#include <hip/hip_runtime.h>
#include <hip/hip_bf16.h>
#include <math.h>

// Problem constants (fixed by reference setup)
#define S_LEN   1024
#define BATCH   2
#define DMODEL  1024
#define NHEADS  16
#define HDIM    64
#define BHEADS  32          // BATCH*NHEADS
#define LP1     4           // 1 + L layers
#define ROWS_PL 2048        // S*B rows per layer

typedef __attribute__((ext_vector_type(8)))  short bf16x8;   // 8 bf16 = 4 VGPRs
typedef __attribute__((ext_vector_type(4)))  float f32x4;
typedef __attribute__((ext_vector_type(16))) float f32x16;

__device__ inline ushort bf16_rne(float a) {
    unsigned u = __float_as_uint(a);
    return (ushort)((u + 0x7FFFu + ((u >> 16) & 1u)) >> 16);
}
__device__ inline float bf16_up(ushort h) { return __uint_as_float(((unsigned)h) << 16); }
__device__ inline void split_bf16(float a, ushort &hi, ushort &lo) {
    hi = bf16_rne(a);
    lo = bf16_rne(a - bf16_up(hi));
}
// packed f32x2 -> bf16x2 (v_cvt_pk_bf16_f32)
__device__ inline uint pk_bf16(float a, float b) {
    float2 f; f.x = a; f.y = b;
    __hip_bfloat162 h = __float22bfloat162_rn(f);
    return *reinterpret_cast<uint*>(&h);
}
// raw v_exp_f32 (no denormal fixup path)
#if __has_builtin(__builtin_amdgcn_exp2f)
__device__ inline float fast_exp2(float x) { return __builtin_amdgcn_exp2f(x); }
#else
__device__ inline float fast_exp2(float x) { return exp2f(x); }
#endif

// v_permlane32_swap_b32 a, b:  a[32:63] <- b[0:31] ; b[0:31] <- a[32:63]
// (verified on HW in rounds 2-14: passed with identical absmax)
__device__ inline void permswap(uint &a, uint &b) {
    asm("v_permlane32_swap_b32 %0, %1" : "+v"(a), "+v"(b));
}

// Async global->LDS, 16 B per lane. HW places lane i at lds_base + i*16.
__device__ inline void glds16(const ushort* g, ushort* l) {
    __builtin_amdgcn_global_load_lds(
        (const __attribute__((address_space(1))) void*)g,
        (__attribute__((address_space(3))) void*)l, 16, 0, 0);
}

// Counted-vmcnt barrier (T4): wait for all but N newest VMEM ops, then raw
// barrier. Never drains the in-flight next-stage loads (the m97-structure
// stall). FIFO retirement guarantees the needed stage (always among the
// oldest) is complete; extra compiler VMEM only makes the wait stricter.
__device__ inline void wait4_barrier() {
    asm volatile("s_waitcnt vmcnt(4)" ::: "memory");
    __builtin_amdgcn_s_barrier();
    __builtin_amdgcn_sched_barrier(0);
}
__device__ inline void wait0_barrier() {
    asm volatile("s_waitcnt vmcnt(0)" ::: "memory");
    __builtin_amdgcn_s_barrier();
    __builtin_amdgcn_sched_barrier(0);
}

// hd^-0.5 * log2(e), folded into the Q projection epilogue
#define SCLF 0.18033688011112042f

// ---------------------------------------------------------------------------
// One-shot pre-split, flat exact grid (no idle blocks):
//   bid    0..1023  -> x        -> XsH
//   bid 1024..4095  -> lo       -> XsH+2M
//   bid 4096..6143  -> weights: z=(bid-4096)>>9 in {Wq,Wk,Wv,Wo}, hi plane;
//                      Wq/Wo also write the lo plane (WL).
// ---------------------------------------------------------------------------
__global__ __launch_bounds__(256)
void presplit(const float* __restrict__ x, const float* __restrict__ lo,
              const float* __restrict__ Wq, const float* __restrict__ Wk,
              const float* __restrict__ Wv, const float* __restrict__ Wo,
              ushort* __restrict__ XsH, ushort* __restrict__ WH,
              ushort* __restrict__ WL)
{
    const int bid = blockIdx.x;
    const float* src; ushort* dh; ushort* dl = nullptr; int local;
    if (bid < 1024)      { src = x;  dh = XsH;           local = bid; }
    else if (bid < 4096) { src = lo; dh = XsH + 2097152; local = bid - 1024; }
    else {
        const int z = (bid - 4096) >> 9;          // 0..3 -> Wq,Wk,Wv,Wo
        local = (bid - 4096) & 511;
        const float* wsrc[4] = { Wq, Wk, Wv, Wo };
        src = wsrc[z];
        dh = WH + (size_t)z * 1048576;
        if (z == 0 || z == 3) dl = WL + (size_t)z * 1048576;
    }
    const int i = (local * 256 + threadIdx.x) * 8;
    float v[8];
    *(float4*)&v[0] = *(const float4*)(src + i);
    *(float4*)&v[4] = *(const float4*)(src + i + 4);
    ushort h[8];
    #pragma unroll
    for (int j = 0; j < 8; ++j) h[j] = bf16_rne(v[j]);
    *(uint4*)(dh + i) = *(uint4*)h;
    if (dl) {
        ushort l[8];
        #pragma unroll
        for (int j = 0; j < 8; ++j) l[j] = bf16_rne(v[j] - bf16_up(h[j]));
        *(uint4*)(dl + i) = *(uint4*)l;
    }
}

// ---------------------------------------------------------------------------
// MERGED Q + KV projection, one dispatch, grid 768. LPT: KV blocks (bid
// 0..511) first, Q blocks (512..767) fill the tail. XCD-aware grouping
// (bid&7 = HW XCD; round 13: FETCH 86 -> 43 MB).
// COUNTED-VMCNT PIPELINE (T4): raw s_barrier + s_waitcnt vmcnt(4) -- the
// next stage's loads stay in flight across the barrier instead of being
// drained (the structural stall of the __syncthreads versions).
//   KV path: A double-buffered (2x8KB), K/V weights TRIPLE-buffered
//            (3x16KB) -> 64 KB LDS exactly; weights get 2 iterations of
//            latency cover, A gets 1.
//   Q path:  uniform 3-stage buffers (3x16KB = 48 KB of the same pool).
// ---------------------------------------------------------------------------
__global__ __launch_bounds__(256, 2)
void proj_qkv(const ushort* __restrict__ XsH,
              const ushort* __restrict__ WH, const ushort* __restrict__ WL,
              const float* __restrict__ bq, const float* __restrict__ bk,
              const float* __restrict__ bv,
              ushort* __restrict__ qhb, ushort* __restrict__ qlb,
              ushort* __restrict__ kout, ushort* __restrict__ vout)
{
    __shared__ ushort smem[32768];       // 64 KB
    const int bid = blockIdx.x;
    const int t   = threadIdx.x;
    const int wv  = t >> 6, lane = t & 63;
    const int quad = lane >> 4, r = lane & 15;
    const int lrow = lane >> 2;
    const int lch  = ((lane & 3) ^ (lrow & 3) ^ ((lrow >> 2) & 3)) * 8;
    const int q0x  = ((quad ^ (r & 3) ^ ((r >> 2) & 3)) << 3);
    const int cn   = lane & 15;

    if (bid >= 512) {
        // ========== Q path (BM=128, BN=64, hi+lo weights, 3-stage) ==========
        const int fid = bid - 512;                   // 0..255
        const int xcd = fid & 7, idx = fid >> 3;     // idx in [0,32)
        const int mt  = xcd * 2 + (idx >> 4);        // 0..15
        const int nt  = idx & 15;                    // 0..15
        const int m0 = mt * 128, n0 = nt * 64;

        const int wm = wv & 1, wn = wv >> 1;
        const int mBase = wm * 64, nBase = wn * 32;

        const ushort* Asrc0 = XsH + (size_t)(m0 + wv * 16 + lrow) * DMODEL + lch;
        const ushort* Asrc1 = Asrc0 + (size_t)64 * DMODEL;
        const ushort* Bhsrc = WH  + (size_t)(n0 + wv * 16 + lrow) * DMODEL + lch;
        const ushort* Blsrc = WL  + (size_t)(n0 + wv * 16 + lrow) * DMODEL + lch;

        f32x4 acc[4][2];
        #pragma unroll
        for (int i = 0; i < 4; ++i)
            #pragma unroll
            for (int j = 0; j < 2; ++j) acc[i][j] = (f32x4){0.f, 0.f, 0.f, 0.f};

        // stage s layout at s*8192: A[128][32] @0, Bh[64][32] @4096, Bl @6144
        // 4 glds per stage
        #pragma unroll
        for (int s = 0; s < 2; ++s) {
            ushort* sb = smem + s * 8192;
            const int off = s * 32;
            glds16(Asrc0 + off, sb        + wv * 512);
            glds16(Asrc1 + off, sb + 2048 + wv * 512);
            glds16(Bhsrc + off, sb + 4096 + wv * 512);
            glds16(Blsrc + off, sb + 6144 + wv * 512);
        }

        for (int k = 0; k < 32; ++k) {
            if (k < 31) wait4_barrier(); else wait0_barrier();
            if (k + 2 < 32) {
                ushort* sb = smem + ((k + 2) % 3) * 8192;
                const int off = (k + 2) * 32;
                glds16(Asrc0 + off, sb        + wv * 512);
                glds16(Asrc1 + off, sb + 2048 + wv * 512);
                glds16(Bhsrc + off, sb + 4096 + wv * 512);
                glds16(Blsrc + off, sb + 6144 + wv * 512);
            }
            const ushort* Ah = smem + (k % 3) * 8192;
            const ushort* Bh = Ah + 4096;
            const ushort* Bl = Ah + 6144;
            bf16x8 fa[4], fbh[2], fbl[2];
            #pragma unroll
            for (int i = 0; i < 4; ++i)
                fa[i] = *(const bf16x8*)&Ah[(mBase + i * 16 + r) * 32 + q0x];
            #pragma unroll
            for (int j = 0; j < 2; ++j) {
                fbh[j] = *(const bf16x8*)&Bh[(nBase + j * 16 + r) * 32 + q0x];
                fbl[j] = *(const bf16x8*)&Bl[(nBase + j * 16 + r) * 32 + q0x];
            }
            #pragma unroll
            for (int i = 0; i < 4; ++i)
                #pragma unroll
                for (int j = 0; j < 2; ++j) {
                    acc[i][j] = __builtin_amdgcn_mfma_f32_16x16x32_bf16(fa[i], fbh[j], acc[i][j], 0, 0, 0);
                    acc[i][j] = __builtin_amdgcn_mfma_f32_16x16x32_bf16(fa[i], fbl[j], acc[i][j], 0, 0, 0);
                }
        }

        #pragma unroll
        for (int j = 0; j < 2; ++j) {
            const int n = n0 + nBase + j * 16 + cn;
            const float bvv = bq[n];
            #pragma unroll
            for (int i = 0; i < 4; ++i) {
                const int mrow = m0 + mBase + i * 16 + quad * 4;
                #pragma unroll
                for (int g = 0; g < 4; ++g) {
                    const int m = mrow + g;
                    const float val = (acc[i][j][g] + bvv) * SCLF;  // fold attn scale
                    const int s = m >> 1, b = m & 1;
                    const int bh = b * 16 + (n >> 6), e = n & 63;
                    const size_t idx2 = (((size_t)bh * S_LEN) + s) * HDIM + e;
                    ushort hi, lov; split_bf16(val, hi, lov);
                    qhb[idx2] = hi; qlb[idx2] = lov;
                }
            }
        }
    } else {
        // ==== KV path (BM=128, BN=128, hi-only; A 2-buf, B 3-buf) ====
        const int xcd = bid & 7, idx = bid >> 3;     // idx in [0,64)
        const int mt  = xcd * 8 + (idx >> 3);        // 0..63
        const int nt  = idx & 7;                     // 0..7
        const int m0 = mt * 128, n0 = nt * 128;
        const int lyr = m0 >> 11;

        const int wm = wv & 1, wn = wv >> 1;
        const int mBase = wm * 64, nBase = wn * 64;

        const ushort* KWh = WH + 1048576;
        const ushort* VWh = WH + 2097152;
        const ushort* Asrc0 = XsH + (size_t)(m0 + wv * 16 + lrow) * DMODEL + lch;
        const ushort* Asrc1 = Asrc0 + (size_t)64 * DMODEL;
        const ushort* Bw[2] = { KWh, VWh };
        const ushort* Bsrc[2][2];
        #pragma unroll
        for (int p = 0; p < 2; ++p)
            #pragma unroll
            for (int seg = 0; seg < 2; ++seg)
                Bsrc[p][seg] = Bw[p] + (size_t)(n0 + wv * 32 + seg * 16 + lrow) * DMODEL + lch;

        f32x4 aK[4][4], aV[4][4];
        #pragma unroll
        for (int i = 0; i < 4; ++i)
            #pragma unroll
            for (int j = 0; j < 4; ++j) {
                aK[i][j] = (f32x4){0.f, 0.f, 0.f, 0.f};
                aV[i][j] = (f32x4){0.f, 0.f, 0.f, 0.f};
            }

        // A buf s at (s&1)*4096 (128x32). B buf s at 8192 + (s%3)*8192:
        // K plane @ +0, V plane @ +4096. Issue order: A(2) then B(4).
        // prologue: A(0), B(0), B(1)
        {
            ushort* ab = smem;                       // A buf 0
            glds16(Asrc0, ab        + wv * 512);
            glds16(Asrc1, ab + 2048 + wv * 512);
            #pragma unroll
            for (int s = 0; s < 2; ++s) {
                ushort* bb = smem + 8192 + s * 8192;
                const int off = s * 32;
                #pragma unroll
                for (int p = 0; p < 2; ++p)
                    #pragma unroll
                    for (int seg = 0; seg < 2; ++seg)
                        glds16(Bsrc[p][seg] + off, bb + p * 4096 + (wv * 2 + seg) * 512);
            }
        }

        for (int k = 0; k < 32; ++k) {
            if (k < 31) wait4_barrier(); else wait0_barrier();
            if (k + 1 < 32) {                        // A(k+1) -> buf (k+1)&1
                ushort* ab = smem + ((k + 1) & 1) * 4096;
                const int off = (k + 1) * 32;
                glds16(Asrc0 + off, ab        + wv * 512);
                glds16(Asrc1 + off, ab + 2048 + wv * 512);
            }
            if (k + 2 < 32) {                        // B(k+2) -> buf (k+2)%3
                ushort* bb = smem + 8192 + ((k + 2) % 3) * 8192;
                const int off = (k + 2) * 32;
                #pragma unroll
                for (int p = 0; p < 2; ++p)
                    #pragma unroll
                    for (int seg = 0; seg < 2; ++seg)
                        glds16(Bsrc[p][seg] + off, bb + p * 4096 + (wv * 2 + seg) * 512);
            }
            const ushort* Ah = smem + (k & 1) * 4096;
            const ushort* Bb = smem + 8192 + (k % 3) * 8192;

            bf16x8 fa[4];
            #pragma unroll
            for (int i = 0; i < 4; ++i)
                fa[i] = *(const bf16x8*)&Ah[(mBase + i * 16 + r) * 32 + q0x];
            #pragma unroll
            for (int j = 0; j < 4; ++j) {
                const int off2 = (nBase + j * 16 + r) * 32 + q0x;
                const bf16x8 fkh = *(const bf16x8*)&Bb[off2];
                const bf16x8 fvh = *(const bf16x8*)&Bb[4096 + off2];
                #pragma unroll
                for (int i = 0; i < 4; ++i) {
                    aK[i][j] = __builtin_amdgcn_mfma_f32_16x16x32_bf16(fa[i], fkh, aK[i][j], 0, 0, 0);
                    aV[i][j] = __builtin_amdgcn_mfma_f32_16x16x32_bf16(fa[i], fvh, aV[i][j], 0, 0, 0);
                }
            }
        }

        // ---- K epilogue: fragment-linear [bhI][kt][es][lane][8] ----
        #pragma unroll
        for (int j = 0; j < 4; ++j) {
            const int n = n0 + nBase + j * 16 + cn;
            const float bb = bk[n];
            const int e    = n & 63;
            const int es_k = e >> 4, half_k = (e >> 3) & 1, j_k = e & 7;
            const int h    = n >> 6;
            #pragma unroll
            for (int i = 0; i < 4; ++i) {
                #pragma unroll
                for (int g = 0; g < 4; ++g) {
                    const int m = m0 + mBase + i * 16 + quad * 4 + g;
                    const int rem = m & 2047, s = rem >> 1, b = rem & 1;
                    const int bhI = lyr * 32 + b * 16 + h;
                    const int kt  = s >> 5;
                    const int lnk = half_k * 32 + (s & 31);
                    kout[(size_t)bhI * 65536 + (size_t)(kt * 4 + es_k) * 512 + lnk * 8 + j_k]
                        = bf16_rne(aK[i][j][g] + bb);
                }
            }
        }

        // ---- V epilogue: transpose via LDS [128][130], fragment-linear ----
        ushort* T = smem;   // 128*130 = 16,640 ushorts <= 32,768 total
        __syncthreads();
        #pragma unroll
        for (int j = 0; j < 4; ++j) {
            const int nloc = nBase + j * 16 + cn;
            const float bb = bv[n0 + nloc];
            #pragma unroll
            for (int i = 0; i < 4; ++i) {
                #pragma unroll
                for (int g = 0; g < 4; ++g) {
                    const int mloc = mBase + i * 16 + quad * 4 + g;
                    T[nloc * 130 + mloc] = bf16_rne(aV[i][j][g] + bb);
                }
            }
        }
        __syncthreads();
        {
            const int nloc = t >> 1, bsel = t & 1;
            const int n = n0 + nloc, h = n >> 6;
            const int e = n & 63;
            const int dg = e >> 5, lid_v = e & 31;
            const int s0g = (m0 & 2047) >> 1;      // multiple of 64
            const int kt0 = s0g >> 5;
            const int bhI = lyr * 32 + bsel * 16 + h;
            #pragma unroll
            for (int c = 0; c < 8; ++c) {
                ushort tmp[8];
                #pragma unroll
                for (int j = 0; j < 8; ++j)
                    tmp[j] = T[nloc * 130 + 2 * (c * 8 + j) + bsel];
                const int kt = kt0 + (c >> 2);
                const int c2 = c & 3;
                const int ks = c2 >> 1, hv = c2 & 1;
                ushort* dstb = vout + (size_t)bhI * 65536 + (size_t)kt * 2048;
                *(uint4*)(dstb + (ks * 2 + dg) * 512 + (hv * 32 + lid_v) * 8) = *(uint4*)tmp;
            }
        }
    }
}

// ---------------------------------------------------------------------------
// O projection, BM=128, BN=64, grid 256, XCD-grouped, 3-STAGE counted-vmcnt
// pipeline (48 KB LDS). fp32 row-major out[m][n].
// ---------------------------------------------------------------------------
__global__ __launch_bounds__(256)
void proj_o(const ushort* __restrict__ Abf,
            const ushort* __restrict__ Bhg, const ushort* __restrict__ Blg,
            const float* __restrict__ bias, float* __restrict__ outf)
{
    __shared__ ushort smem[3][8192];     // 3 stages x 16 KB = 48 KB

    const int fid = blockIdx.x;                  // 0..255
    const int xcd = fid & 7, idx = fid >> 3;     // idx in [0,32)
    const int mt  = xcd * 2 + (idx >> 4);        // 0..15
    const int nt  = idx & 15;                    // 0..15
    const int m0 = mt * 128, n0 = nt * 64;

    const int t  = threadIdx.x;
    const int wv = t >> 6, lane = t & 63;
    const int quad = lane >> 4, r = lane & 15;
    const int wm = wv & 1, wn = wv >> 1;
    const int mBase = wm * 64, nBase = wn * 32;

    const int lrow = lane >> 2;
    const int lch  = ((lane & 3) ^ (lrow & 3) ^ ((lrow >> 2) & 3)) * 8;
    const ushort* Asrc0 = Abf + (size_t)(m0 + wv * 16 + lrow) * DMODEL + lch;
    const ushort* Asrc1 = Asrc0 + (size_t)64 * DMODEL;
    const ushort* Bhsrc = Bhg + (size_t)(n0 + wv * 16 + lrow) * DMODEL + lch;
    const ushort* Blsrc = Blg + (size_t)(n0 + wv * 16 + lrow) * DMODEL + lch;

    const int q0x = ((quad ^ (r & 3) ^ ((r >> 2) & 3)) << 3);
    f32x4 acc[4][2];
    #pragma unroll
    for (int i = 0; i < 4; ++i)
        #pragma unroll
        for (int j = 0; j < 2; ++j) acc[i][j] = (f32x4){0.f, 0.f, 0.f, 0.f};

    #pragma unroll
    for (int s = 0; s < 2; ++s) {
        ushort* sb = smem[s];
        const int off = s * 32;
        glds16(Asrc0 + off, sb        + wv * 512);
        glds16(Asrc1 + off, sb + 2048 + wv * 512);
        glds16(Bhsrc + off, sb + 4096 + wv * 512);
        glds16(Blsrc + off, sb + 6144 + wv * 512);
    }

    for (int k = 0; k < 32; ++k) {
        if (k < 31) wait4_barrier(); else wait0_barrier();
        if (k + 2 < 32) {
            ushort* sb = smem[(k + 2) % 3];
            const int off = (k + 2) * 32;
            glds16(Asrc0 + off, sb        + wv * 512);
            glds16(Asrc1 + off, sb + 2048 + wv * 512);
            glds16(Bhsrc + off, sb + 4096 + wv * 512);
            glds16(Blsrc + off, sb + 6144 + wv * 512);
        }
        const ushort* Ah = smem[k % 3];
        const ushort* Bh = Ah + 4096;
        const ushort* Bl = Ah + 6144;
        bf16x8 fa[4], fbh[2], fbl[2];
        #pragma unroll
        for (int i = 0; i < 4; ++i)
            fa[i] = *(const bf16x8*)&Ah[(mBase + i * 16 + r) * 32 + q0x];
        #pragma unroll
        for (int j = 0; j < 2; ++j) {
            fbh[j] = *(const bf16x8*)&Bh[(nBase + j * 16 + r) * 32 + q0x];
            fbl[j] = *(const bf16x8*)&Bl[(nBase + j * 16 + r) * 32 + q0x];
        }
        #pragma unroll
        for (int i = 0; i < 4; ++i)
            #pragma unroll
            for (int j = 0; j < 2; ++j) {
                acc[i][j] = __builtin_amdgcn_mfma_f32_16x16x32_bf16(fa[i], fbh[j], acc[i][j], 0, 0, 0);
                acc[i][j] = __builtin_amdgcn_mfma_f32_16x16x32_bf16(fa[i], fbl[j], acc[i][j], 0, 0, 0);
            }
    }

    const int cn = lane & 15;
    #pragma unroll
    for (int j = 0; j < 2; ++j) {
        const int n = n0 + nBase + j * 16 + cn;
        const float bvv = bias[n];
        #pragma unroll
        for (int i = 0; i < 4; ++i) {
            const int mrow = m0 + mBase + i * 16 + quad * 4;
            #pragma unroll
            for (int g = 0; g < 4; ++g)
                outf[(size_t)(mrow + g) * DMODEL + n] = acc[i][j][g] + bvv;
        }
    }
}

// ---------------------------------------------------------------------------
// MFMA flash attention, swapped-operand layout (zero LDS, zero barriers),
// u=2 query tiles per wave (64 q), software-pipelined, FRAGMENT-LINEAR K/V
// (coalesced base+lane*16B loads). QK chains seeded with a persistent zero
// C-vector. Grid 512, XCD-swizzled. 2 waves/SIMD is the register-imposed
// occupancy ceiling (unified VGPR+AGPR footprint ~250/wave; round-11's
// (256,4) cap spilled to scratch: 2 GB traffic, 7x slower).
// ---------------------------------------------------------------------------
__global__ __launch_bounds__(256, 2)
void attn_mfma(const ushort* __restrict__ qhg, const ushort* __restrict__ qlg,
               const ushort* __restrict__ kh, const ushort* __restrict__ vth,
               const float* __restrict__ lwraw, float* __restrict__ part)
{
    const int t    = threadIdx.x;
    const int wv   = t >> 6, lane = t & 63;
    const int half = lane >> 5, lid = lane & 31;

    const int fid  = blockIdx.x;                 // 512 blocks
    const int xcd  = fid & 7, slot = fid >> 3;   // slot in [0,64)
    const int pair = xcd * 16 + (slot >> 2);     // 16 (bh,l) pairs per XCD
    const int qt   = slot & 3;                   // 4 q-tiles of 256 per pair
    const int bh   = pair & 31, l = pair >> 5;
    const int qbase = qt * 256 + wv * 64;        // wave owns 64 queries

    float wl;
    {
        float v[LP1], wm = -3.0e38f;
        #pragma unroll
        for (int i = 0; i < LP1; ++i) { v[i] = lwraw[i]; wm = fmaxf(wm, v[i]); }
        float ws = 0.f;
        #pragma unroll
        for (int i = 0; i < LP1; ++i) { v[i] = __expf(v[i] - wm); ws += v[i]; }
        wl = v[l] / ws;
    }

    // Q fragments (B-frag: lane owns query row qbase+u*32+lid, 8 dims/frag)
    bf16x8 qh[2][4], ql[2][4];
    #pragma unroll
    for (int u = 0; u < 2; ++u) {
        const size_t qoff = ((size_t)bh * S_LEN + qbase + u * 32 + lid) * HDIM + half * 8;
        #pragma unroll
        for (int es = 0; es < 4; ++es) {
            qh[u][es] = *(const bf16x8*)(qhg + qoff + es * 16);
            ql[u][es] = *(const bf16x8*)(qlg + qoff + es * 16);
        }
    }

    f32x16 o[2][2];
    #pragma unroll
    for (int u = 0; u < 2; ++u)
        #pragma unroll
        for (int dg = 0; dg < 2; ++dg)
            #pragma unroll
            for (int i = 0; i < 16; ++i) o[u][dg][i] = 0.f;
    float ls[2] = {0.f, 0.f};

    // persistent zero C-operand: seeds each QK chain, never re-written
    f32x16 zf;
    #pragma unroll
    for (int i = 0; i < 16; ++i) zf[i] = 0.f;

    // fragment-linear bases: every load below is base + lane*16B (coalesced)
    const size_t kvo = (size_t)(l * BHEADS + bh) * S_LEN * HDIM;
    const ushort* kfb = kh  + kvo + (size_t)lane * 8;
    const ushort* vfb = vth + kvo + (size_t)lane * 8;

    // ---- prologue: K(0) -> kb; sa = QK(K(0)); K(1) -> kn ----
    bf16x8 kb[4], kn[4];
    #pragma unroll
    for (int es = 0; es < 4; ++es)
        kb[es] = *(const bf16x8*)(kfb + es * 512);
    #pragma unroll
    for (int es = 0; es < 4; ++es)
        kn[es] = *(const bf16x8*)(kfb + 2048 + es * 512);

    f32x16 sa[2];
    #pragma unroll
    for (int es = 0; es < 4; ++es)
        #pragma unroll
        for (int u = 0; u < 2; ++u) {
            sa[u] = __builtin_amdgcn_mfma_f32_32x32x16_bf16(kb[es], qh[u][es],
                                                            es == 0 ? zf : sa[u], 0, 0, 0);
            sa[u] = __builtin_amdgcn_mfma_f32_32x32x16_bf16(kb[es], ql[u][es], sa[u], 0, 0, 0);
        }

    for (int kt = 0; kt < 32; ++kt) {
        // ---- V(kt) loads: coalesced, issued early, consumed by PV ----
        bf16x8 vb[2][2];
        {
            const ushort* vp = vfb + (size_t)kt * 2048;
            #pragma unroll
            for (int ks = 0; ks < 2; ++ks)
                #pragma unroll
                for (int dg = 0; dg < 2; ++dg)
                    vb[ks][dg] = *(const bf16x8*)(vp + (ks * 2 + dg) * 512);
        }

        // ---- softmax(sa of kt) -> pf[2][2], ls; sa dead afterwards ----
        // sa[u] = S^T[k][q]: lane owns col q, reg r -> k=(r&3)+8*(r>>2)+4*half
        bf16x8 pf[2][2];
        #pragma unroll
        for (int ks = 0; ks < 2; ++ks) {
            #pragma unroll
            for (int u = 0; u < 2; ++u) {
                const float p0 = fast_exp2(sa[u][8 * ks + 0]);
                const float p1 = fast_exp2(sa[u][8 * ks + 1]);
                const float p2 = fast_exp2(sa[u][8 * ks + 2]);
                const float p3 = fast_exp2(sa[u][8 * ks + 3]);
                const float p4 = fast_exp2(sa[u][8 * ks + 4]);
                const float p5 = fast_exp2(sa[u][8 * ks + 5]);
                const float p6 = fast_exp2(sa[u][8 * ks + 6]);
                const float p7 = fast_exp2(sa[u][8 * ks + 7]);
                ls[u] += ((p0 + p1) + (p2 + p3)) + ((p4 + p5) + (p6 + p7));

                // Own regs (local k within the 16-key group):
                //   half=0: a0={0,1} a1={2,3} b0={8,9}  b1={10,11}
                //   half=1: a0={4,5} a1={6,7} b0={12,13} b1={14,15}
                // Lane needs k = half*8 + 0..7 of column q=lid.
                uint a0 = pk_bf16(p0, p1);
                uint a1 = pk_bf16(p2, p3);
                uint b0 = pk_bf16(p4, p5);
                uint b1 = pk_bf16(p6, p7);
                // a[32:63] <- b[0:31]; b[0:31] <- a[32:63]:
                //   a0 -> half0:{0,1}  half1:{8,9}   = W0
                //   b0 -> half0:{4,5}  half1:{12,13} = W2
                permswap(a0, b0);
                permswap(a1, b1);            // a1 = W1, b1 = W3
                union { uint w[4]; bf16x8 v; } pu;
                pu.w[0] = a0; pu.w[1] = a1; pu.w[2] = b0; pu.w[3] = b1;
                pf[ks][u] = pu.v;
            }
        }

        // ---- advance K: kb <- kn, prefetch K(kt+2), coalesced ----
        #pragma unroll
        for (int es = 0; es < 4; ++es) kb[es] = kn[es];
        {
            const ushort* kp = kfb + (size_t)((kt + 2) & 31) * 2048;
            #pragma unroll
            for (int es = 0; es < 4; ++es) kn[es] = *(const bf16x8*)(kp + es * 512);
        }

        // ---- QK(kt+1) -> sa (zf-seeded; kt=31 computes an unused tile) ----
        __builtin_amdgcn_s_setprio(1);
        #pragma unroll
        for (int es = 0; es < 4; ++es)
            #pragma unroll
            for (int u = 0; u < 2; ++u) {
                sa[u] = __builtin_amdgcn_mfma_f32_32x32x16_bf16(kb[es], qh[u][es],
                                                                es == 0 ? zf : sa[u], 0, 0, 0);
                sa[u] = __builtin_amdgcn_mfma_f32_32x32x16_bf16(kb[es], ql[u][es], sa[u], 0, 0, 0);
            }
        __builtin_amdgcn_s_setprio(0);

        // ---- PV(kt): o += V^T(kt) x P^T(kt) ----
        __builtin_amdgcn_s_setprio(1);
        #pragma unroll
        for (int ks = 0; ks < 2; ++ks)
            #pragma unroll
            for (int dg = 0; dg < 2; ++dg)
                #pragma unroll
                for (int u = 0; u < 2; ++u)
                    o[u][dg] = __builtin_amdgcn_mfma_f32_32x32x16_bf16(vb[ks][dg], pf[ks][u], o[u][dg], 0, 0, 0);
        __builtin_amdgcn_s_setprio(0);
    }

    // ---- epilogue: combine half-lane partial sums, scale, store O^T ----
    const int b = bh >> 4, hh = bh & 15;
    #pragma unroll
    for (int u = 0; u < 2; ++u) {
        float lsv = ls[u];
        lsv += __shfl_xor(lsv, 32);
        const float sc = wl / lsv;
        const int q = qbase + u * 32 + lid;
        float* pb = part + (size_t)l * (ROWS_PL * DMODEL)
                  + ((size_t)q * BATCH + b) * DMODEL + hh * HDIM;
        #pragma unroll
        for (int dg = 0; dg < 2; ++dg)
            #pragma unroll
            for (int rq = 0; rq < 4; ++rq) {
                float4 vv;
                vv.x = o[u][dg][rq * 4 + 0] * sc;
                vv.y = o[u][dg][rq * 4 + 1] * sc;
                vv.z = o[u][dg][rq * 4 + 2] * sc;
                vv.w = o[u][dg][rq * 4 + 3] * sc;
                *(float4*)(pb + dg * 32 + rq * 8 + half * 4) = vv;
            }
    }
}

// ---------------------------------------------------------------------------
// Sum the 4 layer partials -> bf16 hi plane for the O projection.
// ---------------------------------------------------------------------------
__global__ __launch_bounds__(256)
void sum_y(const float* __restrict__ part, ushort* __restrict__ YH)
{
    const int i = (blockIdx.x * 256 + threadIdx.x) * 8;
    float acc[8];
    #pragma unroll
    for (int c = 0; c < 2; ++c) {
        float4 s = *(const float4*)(part + i + c * 4);
        #pragma unroll
        for (int l = 1; l < LP1; ++l) {
            const float4 p = *(const float4*)(part + (size_t)l * 2097152 + i + c * 4);
            s.x += p.x; s.y += p.y; s.z += p.z; s.w += p.w;
        }
        acc[c * 4 + 0] = s.x; acc[c * 4 + 1] = s.y;
        acc[c * 4 + 2] = s.z; acc[c * 4 + 3] = s.w;
    }
    uint out[4];
    #pragma unroll
    for (int c = 0; c < 4; ++c) out[c] = pk_bf16(acc[c * 2], acc[c * 2 + 1]);
    *(uint4*)(YH + i) = *(uint4*)out;
}

// ---------------------------------------------------------------------------
extern "C" void kernel_launch(void* const* d_in, const int* in_sizes, int n_in,
                              void* d_out, int out_size, void* d_ws, size_t ws_size,
                              hipStream_t stream) {
    const float* x  = (const float*)d_in[0];
    const float* lo = (const float*)d_in[1];
    const float* Wq = (const float*)d_in[2];
    const float* bq = (const float*)d_in[3];
    const float* Wk = (const float*)d_in[4];
    const float* bk = (const float*)d_in[5];
    const float* Wv = (const float*)d_in[6];
    const float* bv = (const float*)d_in[7];
    const float* Wo = (const float*)d_in[8];
    const float* bo = (const float*)d_in[9];
    const float* lw = (const float*)d_in[10];
    float* out = (float*)d_out;

    char* ws = (char*)d_ws;
    ushort* XsH  = (ushort*)(ws);                          // 16,777,216 B
    ushort* WH   = (ushort*)(ws + 16777216);               //  8,388,608 B
    ushort* WL   = (ushort*)(ws + 25165824);               //  8,388,608 B (Wq/Wo only)
    ushort* qhb  = (ushort*)(ws + 33554432);               //  4,194,304 B
    ushort* qlb  = (ushort*)(ws + 37748736);               //  4,194,304 B
    ushort* khb  = (ushort*)(ws + 41943040);               // 16,777,216 B
    ushort* vthb = (ushort*)(ws + 58720256);               // 16,777,216 B
    float*  part = (float*)(ws + 75497472);                // 33,554,432 B
    ushort* YH   = (ushort*)(ws + 109051904);              //  4,194,304 B
    // total 113,246,208 B

    dim3 blk(256);
    // Xs -> hi plane; Wq/Wo -> hi+lo; Wk/Wv -> hi only (flat exact grid)
    presplit<<<dim3(6144), blk, 0, stream>>>(x, lo, Wq, Wk, Wv, Wo, XsH, WH, WL);
    // merged Q + KV projections (LPT + XCD grouping + counted-vmcnt pipeline)
    proj_qkv<<<dim3(768), blk, 0, stream>>>(XsH, WH, WL, bq, bk, bv,
                                            qhb, qlb, khb, vthb);
    // attention: 512 XCD-swizzled blocks -> per-layer fp32 partials
    attn_mfma<<<dim3(512), blk, 0, stream>>>(qhb, qlb, khb, vthb, lw, part);
    // reduce 4 partials -> bf16 hi plane
    sum_y<<<dim3(1024), blk, 0, stream>>>(part, YH);
    // output projection (BM=128, XCD-grouped, 3-stage counted-vmcnt)
    proj_o<<<dim3(256), blk, 0, stream>>>(YH, WH + 3145728, WL + 3145728, bo, out);
}